// Round 13
// baseline (760.733 us; speedup 1.0000x reference)
//
#include <hip/hip_runtime.h>
#include <hip/hip_bf16.h>

typedef __hip_bfloat16 bf16;
typedef unsigned short u16;
typedef __attribute__((ext_vector_type(4))) float f32x4;
typedef __attribute__((ext_vector_type(8))) short bf16x8;
typedef __attribute__((ext_vector_type(2))) unsigned int u32x2;

#define MFMA16(a, b, c) __builtin_amdgcn_mfma_f32_16x16x32_bf16((a), (b), (c), 0, 0, 0)

__device__ __forceinline__ float bfu2f(u16 u){
  return __uint_as_float(((unsigned int)u) << 16);
}
__device__ __forceinline__ u16 f2bfu(float x){
  return __builtin_bit_cast(u16, __float2bfloat16(x));
}
__device__ __forceinline__ void gload16(const void* g, const void* l){
  __builtin_amdgcn_global_load_lds(
      (const __attribute__((address_space(1))) unsigned int*)g,
      (__attribute__((address_space(3))) unsigned int*)l, 16, 0, 0);
}

// ---------------------------------------------------------------------------
// cvt: fp32 -> bf16, 8 elems/thread (single matrix)
// ---------------------------------------------------------------------------
__global__ __launch_bounds__(256) void cvt_bf16(
    const float* __restrict__ src, u16* __restrict__ dst, int n8)
{
  int i = blockIdx.x * 256 + threadIdx.x;
  if (i >= n8) return;
  const float4* s = (const float4*)src;
  float4 a = s[i * 2], b = s[i * 2 + 1];
  u16 o[8] = {f2bfu(a.x), f2bfu(a.y), f2bfu(a.z), f2bfu(a.w),
              f2bfu(b.x), f2bfu(b.y), f2bfu(b.z), f2bfu(b.w)};
  *(bf16x8*)(dst + (size_t)i * 8) = *(bf16x8*)o;
}

// cvt for the 3 projection weights in one launch (blockIdx.y selects)
__global__ __launch_bounds__(256) void cvt3_bf16(
    const float* __restrict__ s0, const float* __restrict__ s1, const float* __restrict__ s2,
    u16* __restrict__ d0, u16* __restrict__ d1, u16* __restrict__ d2)
{
  const float* s; u16* d;
  if (blockIdx.y == 0)      { s = s0; d = d0; }
  else if (blockIdx.y == 1) { s = s1; d = d1; }
  else                      { s = s2; d = d2; }
  int i = blockIdx.x * 256 + threadIdx.x;      // < 131072
  const float4* sp = (const float4*)s;
  float4 a = sp[i * 2], b = sp[i * 2 + 1];
  u16 o[8] = {f2bfu(a.x), f2bfu(a.y), f2bfu(a.z), f2bfu(a.w),
              f2bfu(b.x), f2bfu(b.y), f2bfu(b.z), f2bfu(b.w)};
  *(bf16x8*)(d + (size_t)i * 8) = *(bf16x8*)o;
}

// ---------------------------------------------------------------------------
// bf16 MFMA GEMM: C[M x 1024] = A[M x 1024] @ B^T (B stored [1024][1024] row=n)
// 128x128 tile, BK=64, 4 waves (2x2), 4x4 frags of 16x16x32.
// ---------------------------------------------------------------------------
template<int NMAT, bool F32OUT>
__global__ __launch_bounds__(256) void gemm_bt(
    const u16* __restrict__ A,
    const u16* __restrict__ B0, const u16* __restrict__ B1, const u16* __restrict__ B2,
    void* __restrict__ C0, void* __restrict__ C1, void* __restrict__ C2)
{
  const u16* B; void* C;
  if (NMAT == 1 || blockIdx.z == 0){ B = B0; C = C0; }
  else if (blockIdx.z == 1)        { B = B1; C = C1; }
  else                             { B = B2; C = C2; }
  __shared__ char lds[2][2][16384];   // [buf][A=0/B=1][128 rows * 128B]
  const int tid = threadIdx.x;
  const int lane = tid & 63, wv = tid >> 6;
  const int lc = lane & 15, lh = lane >> 4;
  const int wr = wv >> 1, wc = wv & 1;
  const int m0 = blockIdx.x * 128, n0 = blockIdx.y * 128;

  f32x4 acc[4][4];
  #pragma unroll
  for (int mt = 0; mt < 4; mt++)
    #pragma unroll
    for (int nt = 0; nt < 4; nt++) acc[mt][nt] = (f32x4){0.f, 0.f, 0.f, 0.f};

  auto stage = [&](int buf, int k0){
    #pragma unroll
    for (int c = 0; c < 4; c++){
      const int q = wv * 4096 + c * 1024;            // wave-uniform LDS base
      const int row = (q >> 7) + (lane >> 3);        // per-lane row
      const int slot = (lane & 7) ^ (row & 7);       // logical slot to fetch
      gload16(A + (size_t)(m0 + row) * 1024 + k0 + slot * 8, &lds[buf][0][q]);
      gload16(B + (size_t)(n0 + row) * 1024 + k0 + slot * 8, &lds[buf][1][q]);
    }
  };

  stage(0, 0);
  __syncthreads();
  int cur = 0;
  for (int t = 0; t < 16; t++){
    if (t < 15) stage(cur ^ 1, (t + 1) * 64);
    const char* Abuf = lds[cur][0];
    const char* Bbuf = lds[cur][1];
    #pragma unroll
    for (int kk = 0; kk < 2; kk++){
      bf16x8 af[4], bfr[4];
      #pragma unroll
      for (int mt = 0; mt < 4; mt++){
        int r = wr * 64 + mt * 16 + lc;
        int slot = (kk * 4 + lh) ^ (r & 7);
        af[mt] = *(const bf16x8*)(const void*)(Abuf + r * 128 + slot * 16);
      }
      #pragma unroll
      for (int nt = 0; nt < 4; nt++){
        int r = wc * 64 + nt * 16 + lc;
        int slot = (kk * 4 + lh) ^ (r & 7);
        bfr[nt] = *(const bf16x8*)(const void*)(Bbuf + r * 128 + slot * 16);
      }
      #pragma unroll
      for (int mt = 0; mt < 4; mt++)
        #pragma unroll
        for (int nt = 0; nt < 4; nt++)
          acc[mt][nt] = MFMA16(af[mt], bfr[nt], acc[mt][nt]);
    }
    __syncthreads();
    cur ^= 1;
  }

  #pragma unroll
  for (int mt = 0; mt < 4; mt++)
    #pragma unroll
    for (int nt = 0; nt < 4; nt++)
      #pragma unroll
      for (int rg = 0; rg < 4; rg++){
        int row = m0 + wr * 64 + mt * 16 + lh * 4 + rg;
        int col = n0 + wc * 64 + nt * 16 + lc;
        if (F32OUT) ((float*)C)[(size_t)row * 1024 + col] = acc[mt][nt][rg];
        else ((bf16*)C)[(size_t)row * 1024 + col] = __float2bfloat16(acc[mt][nt][rg]);
      }
}

// ---------------------------------------------------------------------------
// K2: beta = sigmoid(x@Wb^T) stored [b][h][l]; mix = sigmoid(x@Wmix^T) [tok][h]
// ---------------------------------------------------------------------------
__global__ __launch_bounds__(256) void small_proj(
    const float* __restrict__ x, const float* __restrict__ Wb,
    const float* __restrict__ Wmix, float* __restrict__ beta, float* __restrict__ mixb)
{
  const int tok = blockIdx.x;
  const int tid = threadIdx.x;
  __shared__ __align__(16) float xrow[1024];
  ((float4*)xrow)[tid] = ((const float4*)(x + (size_t)tok * 1024))[tid];
  __syncthreads();
  const int o = tid >> 5, g = tid & 31;
  const float* Wrow = (o < 4) ? (Wb + (size_t)o * 1024) : (Wmix + (size_t)(o - 4) * 1024);
  float p = 0.f;
  for (int e = g; e < 256; e += 32){
    float4 xv = ((const float4*)xrow)[e];
    float4 wv = ((const float4*)Wrow)[e];
    p += xv.x * wv.x + xv.y * wv.y + xv.z * wv.z + xv.w * wv.w;
  }
  for (int off = 16; off; off >>= 1) p += __shfl_down(p, off, 32);
  if (g == 0){
    float s = 1.f / (1.f + expf(-p));
    int b = tok >> 12, t = tok & 4095;
    if (o < 4) beta[((size_t)(b * 4 + o)) * 4096 + t] = s;
    else       mixb[(size_t)tok * 4 + (o - 4)] = s;
  }
}

// ---------------------------------------------------------------------------
// K3: causal depthwise conv (K=4) + silu, vectorized bf16x8 (8 channels/thread)
// ---------------------------------------------------------------------------
__global__ __launch_bounds__(256) void conv_silu3(
    const bf16* __restrict__ in0, const bf16* __restrict__ in1, const bf16* __restrict__ in2,
    const float* __restrict__ w0, const float* __restrict__ w1, const float* __restrict__ w2,
    bf16* __restrict__ o0, bf16* __restrict__ o1, bf16* __restrict__ o2)
{
  const bf16* in; const float* wc; bf16* out;
  if (blockIdx.y == 0)      { in = in0; wc = w0; out = o0; }
  else if (blockIdx.y == 1) { in = in1; wc = w1; out = o1; }
  else                      { in = in2; wc = w2; out = o2; }
  const int idx8 = blockIdx.x * 256 + threadIdx.x;   // < 2097152
  const int c8 = (idx8 & 127) * 8;
  const int tt = idx8 >> 7;            // b*4096 + t
  const int t  = tt & 4095;
  const u16* inu = (const u16*)in;
  const size_t base = (size_t)tt * 1024 + c8;
  bf16x8 zv = {0, 0, 0, 0, 0, 0, 0, 0};
  bf16x8 x3 = *(const bf16x8*)(const void*)(inu + base);
  bf16x8 x2 = (t >= 1) ? *(const bf16x8*)(const void*)(inu + base - 1024) : zv;
  bf16x8 x1 = (t >= 2) ? *(const bf16x8*)(const void*)(inu + base - 2048) : zv;
  bf16x8 x0 = (t >= 3) ? *(const bf16x8*)(const void*)(inu + base - 3072) : zv;
  u16 o8[8];
  #pragma unroll
  for (int e = 0; e < 8; e++){
    const float4 w4 = ((const float4*)wc)[c8 + e];
    float s = w4.w * bfu2f((u16)x3[e]) + w4.z * bfu2f((u16)x2[e])
            + w4.y * bfu2f((u16)x1[e]) + w4.x * bfu2f((u16)x0[e]);
    s = s / (1.f + expf(-s));
    o8[e] = f2bfu(s);
  }
  *(bf16x8*)(void*)((u16*)out + base) = *(bf16x8*)o8;
}

// ---------------------------------------------------------------------------
// K4: per-chunk prep, MFMA version (unchanged).
// ---------------------------------------------------------------------------
__global__ __launch_bounds__(256, 2) void chunk_prep(
    bf16* __restrict__ qc, const bf16* __restrict__ kc, const bf16* __restrict__ vc,
    const float* __restrict__ beta,
    bf16* __restrict__ u_out, bf16* __restrict__ w_out,
    bf16* __restrict__ Ab, bf16* __restrict__ kTg)
{
  __shared__ char kS[16384], qS[16384];       // [32][256] bf16, row-swizzled
  __shared__ float att[1056];                 // [32][33] fp32
  __shared__ char Th[2048], Tl[2048];         // T hi/lo [32]x64B, group-swizzled
  __shared__ char vTh[8192], vTl[8192];       // vb^T half [128]x64B hi/lo
  __shared__ char wTh[8192], wTl[8192];       // kb^T half
  __shared__ float rnk_s[32], rnq_s[32], bvec[32];

  const int g = blockIdx.x;
  const int ch = g & 127, h = (g >> 7) & 3, b = g >> 9;
  const int tid = threadIdx.x;
  const int l = tid & 63, wv = tid >> 6;
  const int lc = l & 15, lh = l >> 4;
  const int i = tid >> 3, s = tid & 7;        // row, 32-col slice
  const size_t rowbase = ((size_t)(b * 4096 + ch * 32)) * 1024 + (size_t)h * 256;
  const u16* kcu = (const u16*)kc;
  const u16* qcu = (const u16*)qc;
  const u16* vcu = (const u16*)vc;

  // ---- P1: load + row sum-of-squares ----
  bf16x8 kr[4], qr[4], vr[4];
  float ssk = 0.f, ssq = 0.f;
  #pragma unroll
  for (int j4 = 0; j4 < 4; j4++){
    size_t eo = rowbase + (size_t)i * 1024 + s * 32 + j4 * 8;
    kr[j4] = *(const bf16x8*)(const void*)(kcu + eo);
    qr[j4] = *(const bf16x8*)(const void*)(qcu + eo);
    vr[j4] = *(const bf16x8*)(const void*)(vcu + eo);
    #pragma unroll
    for (int e = 0; e < 8; e++){
      float kv = bfu2f((u16)kr[j4][e]); ssk += kv * kv;
      float qv = bfu2f((u16)qr[j4][e]); ssq += qv * qv;
    }
  }
  #pragma unroll
  for (int off = 1; off < 8; off <<= 1){
    ssk += __shfl_xor(ssk, off, 64);
    ssq += __shfl_xor(ssq, off, 64);
  }
  if (s == 0){
    rnk_s[i] = 1.0f / sqrtf(ssk + 1e-6f);
    rnq_s[i] = 1.0f / sqrtf(ssq + 1e-6f);
  }
  if (tid < 32) bvec[tid] = beta[((size_t)(b * 4 + h)) * 4096 + ch * 32 + tid];
  __syncthreads();

  // ---- P2: normalize; stage kS/qS; write qn global; vT/kbT half 0 ----
  const float rk = rnk_s[i], rq = rnq_s[i], bi = bvec[i];
  #pragma unroll
  for (int j4 = 0; j4 < 4; j4++){
    u16 kn8[8], qn8[8];
    #pragma unroll
    for (int e = 0; e < 8; e++){
      kn8[e] = f2bfu(bfu2f((u16)kr[j4][e]) * rk);
      qn8[e] = f2bfu(bfu2f((u16)qr[j4][e]) * rq);
    }
    int byt = (i * 512 + s * 64 + j4 * 16) ^ ((i & 7) << 4);
    *(bf16x8*)(void*)(kS + byt) = *(bf16x8*)kn8;
    *(bf16x8*)(void*)(qS + byt) = *(bf16x8*)qn8;
    *(bf16x8*)(void*)((u16*)qc + rowbase + (size_t)i * 1024 + s * 32 + j4 * 8) = *(bf16x8*)kn8 * 0 + *(bf16x8*)qn8;
  }
  if ((s >> 2) == 0){
    #pragma unroll
    for (int j4 = 0; j4 < 4; j4++)
      #pragma unroll
      for (int e = 0; e < 8; e++){
        int dl = (s & 3) * 32 + j4 * 8 + e;
        float vb = bfu2f((u16)vr[j4][e]) * bi;
        float kb = bfu2f((u16)kr[j4][e]) * rk * bi;
        u16 vh = f2bfu(vb), kh = f2bfu(kb);
        u16 vlo = f2bfu(vb - bfu2f(vh)), klo = f2bfu(kb - bfu2f(kh));
        int byt = dl * 64 + (((i >> 3) ^ ((dl >> 1) & 3)) << 4) + (i & 7) * 2;
        *(u16*)(vTh + byt) = vh; *(u16*)(vTl + byt) = vlo;
        *(u16*)(wTh + byt) = kh; *(u16*)(wTl + byt) = klo;
      }
  }
  __syncthreads();

  // ---- P3: L & A quadrants via MFMA; kTg transpose-out ----
  {
    const int mq = wv >> 1, nq = wv & 1;
    const int rowA = mq * 16 + lc, rowB = nq * 16 + lc;
    const int swA = (rowA & 7) << 4, swB = (rowB & 7) << 4;
    f32x4 accL = (f32x4){0.f, 0.f, 0.f, 0.f};
    f32x4 accA = (f32x4){0.f, 0.f, 0.f, 0.f};
    #pragma unroll
    for (int kt = 0; kt < 8; kt++){
      bf16x8 af  = *(const bf16x8*)(const void*)(kS + ((rowA * 512 + kt * 64 + lh * 16) ^ swA));
      bf16x8 bf_ = *(const bf16x8*)(const void*)(kS + ((rowB * 512 + kt * 64 + lh * 16) ^ swB));
      bf16x8 aq  = *(const bf16x8*)(const void*)(qS + ((rowA * 512 + kt * 64 + lh * 16) ^ swA));
      accL = MFMA16(af, bf_, accL);
      accA = MFMA16(aq, bf_, accA);
    }
    #pragma unroll
    for (int r = 0; r < 4; r++){
      int rr = mq * 16 + lh * 4 + r, cc = nq * 16 + lc;
      att[rr * 33 + cc] = (cc < rr) ? (-bvec[rr] * accL[r]) : 0.f;
      float av = (cc <= rr) ? accA[r] : 0.f;
      ((u16*)Ab)[(size_t)g * 1024 + rr * 32 + cc] = f2bfu(av);
    }
  }
  {
    u16 tmp[32];
    #pragma unroll
    for (int i2 = 0; i2 < 32; i2++)
      tmp[i2] = *(const u16*)(kS + ((i2 * 512 + tid * 2) ^ ((i2 & 7) << 4)));
    #pragma unroll
    for (int j4 = 0; j4 < 4; j4++)
      *(bf16x8*)(void*)((u16*)kTg + (size_t)g * 8192 + tid * 32 + j4 * 8) = *(bf16x8*)(tmp + j4 * 8);
  }
  __syncthreads();

  // ---- P4: wave-0 fp32 forward substitution (barrier-free in-wave) ----
  if (wv == 0 && l < 32){
    for (int ii = 1; ii < 32; ii++){
      float upd = 0.f;
      for (int m = 0; m < ii; m++)
        upd += att[ii * 33 + m] * att[m * 33 + l];
      att[ii * 33 + l] += upd;
    }
    att[l * 33 + l] = 1.0f;   // T = subst(L) + I
  }
  __syncthreads();

  // ---- P5: T -> hi/lo bf16 ----
  #pragma unroll
  for (int z = 0; z < 4; z++){
    int e = tid * 4 + z;
    int row = e >> 5, col = e & 31;
    float f = att[row * 33 + col];
    u16 hh = f2bfu(f), llo = f2bfu(f - bfu2f(hh));
    int byt = row * 64 + ((((col >> 3)) ^ ((row >> 1) & 3)) << 4) + (col & 7) * 2;
    *(u16*)(Th + byt) = hh; *(u16*)(Tl + byt) = llo;
  }
  __syncthreads();

  // ---- P6/P8: u = T@vb, w = T@kb (3-term hi/lo), two dv halves ----
  {
    const int mq = wv >> 1, nsel = wv & 1;
    const int rowA = mq * 16 + lc;
    const int sa = (lh ^ ((rowA >> 1) & 3)) << 4;
    bf16x8 ta = *(const bf16x8*)(const void*)(Th + rowA * 64 + sa);
    bf16x8 tl = *(const bf16x8*)(const void*)(Tl + rowA * 64 + sa);
    #pragma unroll
    for (int half = 0; half < 2; half++){
      if (half == 1){
        __syncthreads();            // all half-0 reads done
        if ((s >> 2) == 1){         // P7: stage half 1
          #pragma unroll
          for (int j4 = 0; j4 < 4; j4++)
            #pragma unroll
            for (int e = 0; e < 8; e++){
              int dl = (s & 3) * 32 + j4 * 8 + e;
              float vb = bfu2f((u16)vr[j4][e]) * bi;
              float kb = bfu2f((u16)kr[j4][e]) * rk * bi;
              u16 vh = f2bfu(vb), kh = f2bfu(kb);
              u16 vlo = f2bfu(vb - bfu2f(vh)), klo = f2bfu(kb - bfu2f(kh));
              int byt = dl * 64 + (((i >> 3) ^ ((dl >> 1) & 3)) << 4) + (i & 7) * 2;
              *(u16*)(vTh + byt) = vh; *(u16*)(vTl + byt) = vlo;
              *(u16*)(wTh + byt) = kh; *(u16*)(wTl + byt) = klo;
            }
        }
        __syncthreads();
      }
      #pragma unroll
      for (int nt = 0; nt < 4; nt++){
        int nl = nsel * 64 + nt * 16;
        int rowB = nl + lc;
        int sb = (lh ^ ((rowB >> 1) & 3)) << 4;
        bf16x8 bh_ = *(const bf16x8*)(const void*)(vTh + rowB * 64 + sb);
        bf16x8 bl_ = *(const bf16x8*)(const void*)(vTl + rowB * 64 + sb);
        f32x4 aU = (f32x4){0.f, 0.f, 0.f, 0.f};
        aU = MFMA16(ta, bh_, aU);
        aU = MFMA16(ta, bl_, aU);
        aU = MFMA16(tl, bh_, aU);
        bf16x8 wh_ = *(const bf16x8*)(const void*)(wTh + rowB * 64 + sb);
        bf16x8 wl_ = *(const bf16x8*)(const void*)(wTl + rowB * 64 + sb);
        f32x4 aW = (f32x4){0.f, 0.f, 0.f, 0.f};
        aW = MFMA16(ta, wh_, aW);
        aW = MFMA16(ta, wl_, aW);
        aW = MFMA16(tl, wh_, aW);
        #pragma unroll
        for (int r = 0; r < 4; r++){
          int row = mq * 16 + lh * 4 + r, col = half * 128 + nl + lc;
          ((u16*)u_out)[rowbase + (size_t)row * 1024 + col] = f2bfu(aU[r]);
          ((u16*)w_out)[rowbase + (size_t)row * 1024 + col] = f2bfu(aW[r]);
        }
      }
    }
  }
}

// ---------------------------------------------------------------------------
// K5: sequential chunk scan, round-13: r9 structure with w/q A-fragments read
// DIRECTLY from global (mirror of the r9-proven kF-direct pattern), removing
// wqbuf LDS (84.5KB -> 18.5KB), all global_load_lds staging, the staging
// swizzle, and shrinking the vmcnt drain at each barrier (~45 -> ~13
// outstanding loads). w/q chunk data (64KB) is L1/L2-resident: the 16 sibling
// vb-blocks of each bh share it on one XCD (r6 swizzle). Arithmetic
// bit-identical to r9/r12.
// ---------------------------------------------------------------------------
__global__ __launch_bounds__(128, 1) void scan_kernel(
    const u16* __restrict__ w_in, const u16* __restrict__ qn,
    const u16* __restrict__ u_in, const bf16* __restrict__ Ab,
    const bf16* __restrict__ kTg, bf16* __restrict__ o_out)
{
  extern __shared__ char smem[];
  char* stbuf  = smem;               // S^T hi 8K | lo 8K ([16 c][512B]) swizzled
  char* untbuf = smem + 16384;       // un^T hi 1280 | lo 1280 ([16 c][80B])

  const int tid = threadIdx.x;                 // 0..127
  const int l = tid & 63, wv = tid >> 6;       // wv 0..1
  const int lc = l & 15, lh = l >> 4;
  const int wg = blockIdx.x;
  const int bh = (wg & 7) * 2 + ((wg >> 3) & 1);  // all 16 vb of a bh on one XCD
  const int vb = wg >> 4;                      // 0..15
  const int h = bh & 3, b = bh >> 2;
  const int c0 = vb * 16;
  const int mw = wv * 16;                      // wave's un-row block

  f32x4 Sf[8];
  #pragma unroll
  for (int mt = 0; mt < 8; mt++) Sf[mt] = (f32x4){0.f, 0.f, 0.f, 0.f};

  const size_t bhElem = (size_t)b * 4096 * 1024 + (size_t)h * 256;
  const u16* kTu = (const u16*)kTg;

  // prologue: zero S^T; chunk-0 u/A frags
  for (int e = tid; e < 4096; e += 128) ((unsigned int*)(void*)stbuf)[e] = 0u;
  u16 cu0 = u_in[bhElem + (size_t)(mw + lh*4 + 0) * 1024 + c0 + lc];
  u16 cu1 = u_in[bhElem + (size_t)(mw + lh*4 + 1) * 1024 + c0 + lc];
  u16 cu2 = u_in[bhElem + (size_t)(mw + lh*4 + 2) * 1024 + c0 + lc];
  u16 cu3 = u_in[bhElem + (size_t)(mw + lh*4 + 3) * 1024 + c0 + lc];
  bf16x8 cAf = *(const bf16x8*)(const void*)(Ab + (size_t)(bh * 128) * 1024 + (mw + lc) * 32 + lh * 8);
  __syncthreads();

  for (int ch = 0; ch < 128; ch++){
    const size_t rowElem = bhElem + (size_t)ch * 32768;
    // current-chunk kT fragments from global (coalesced 16B/lane); consumed
    // after barrier A whose vmcnt(0) drain guarantees arrival
    bf16x8 kF[8];
    {
      const size_t ktCur = (size_t)(bh * 128 + ch) * 8192;
      #pragma unroll
      for (int mt = 0; mt < 8; mt++){
        int rowK = wv * 128 + mt * 16 + lc;
        kF[mt] = *(const bf16x8*)(const void*)(kTu + ktCur + (size_t)rowK * 32 + lh * 8);
      }
    }
    // next-chunk u/A prefetch
    u16 pu0, pu1, pu2, pu3; bf16x8 pAf;
    if (ch < 127){
      const size_t rowN = rowElem + 32768;
      pu0 = u_in[rowN + (size_t)(mw + lh*4 + 0) * 1024 + c0 + lc];
      pu1 = u_in[rowN + (size_t)(mw + lh*4 + 1) * 1024 + c0 + lc];
      pu2 = u_in[rowN + (size_t)(mw + lh*4 + 2) * 1024 + c0 + lc];
      pu3 = u_in[rowN + (size_t)(mw + lh*4 + 3) * 1024 + c0 + lc];
      pAf = *(const bf16x8*)(const void*)(Ab + (size_t)(bh * 128 + ch + 1) * 1024 + (mw + lc) * 32 + lh * 8);
    }

    // fused phase: accU = w@S, accO = q@S (old S), even/odd-kt split chains.
    // w/q A-frags straight from global: row = mw+lc, elems kt*32 + lh*8.
    f32x4 aU0 = (f32x4){0.f,0.f,0.f,0.f}, aU1 = (f32x4){0.f,0.f,0.f,0.f};
    f32x4 aO0 = (f32x4){0.f,0.f,0.f,0.f}, aO1 = (f32x4){0.f,0.f,0.f,0.f};
    {
      const size_t rowOff = rowElem + (size_t)(mw + lc) * 1024 + lh * 8;
      const int swS = (lc & 7) << 4;
      #pragma unroll
      for (int kt = 0; kt < 8; kt++){
        const int kb = kt * 64 + lh * 16;
        bf16x8 aw = *(const bf16x8*)(const void*)(w_in + rowOff + kt * 32);
        bf16x8 aq = *(const bf16x8*)(const void*)(qn + rowOff + kt * 32);
        bf16x8 sh = *(const bf16x8*)(const void*)(stbuf + ((lc * 512 + kb) ^ swS));
        bf16x8 sl = *(const bf16x8*)(const void*)(stbuf + 8192 + ((lc * 512 + kb) ^ swS));
        if (kt & 1){
          aU1 = MFMA16(aw, sh, aU1);
          aU1 = MFMA16(aw, sl, aU1);
          aO1 = MFMA16(aq, sh, aO1);
          aO1 = MFMA16(aq, sl, aO1);
        } else {
          aU0 = MFMA16(aw, sh, aU0);
          aU0 = MFMA16(aw, sl, aU0);
          aO0 = MFMA16(aq, sh, aO0);
          aO0 = MFMA16(aq, sl, aO0);
        }
      }
    }
    f32x4 accO = aO0 + aO1;
    {
      f32x4 accU = aU0 + aU1;
      float v0 = bfu2f(cu0) - accU[0];
      float v1 = bfu2f(cu1) - accU[1];
      float v2 = bfu2f(cu2) - accU[2];
      float v3 = bfu2f(cu3) - accU[3];
      u16 h0 = f2bfu(v0), h1 = f2bfu(v1), h2 = f2bfu(v2), h3 = f2bfu(v3);
      u16 l0 = f2bfu(v0 - bfu2f(h0)), l1 = f2bfu(v1 - bfu2f(h1));
      u16 l2 = f2bfu(v2 - bfu2f(h2)), l3 = f2bfu(v3 - bfu2f(h3));
      unsigned int ph0 = (unsigned)h0 | ((unsigned)h1 << 16), ph1 = (unsigned)h2 | ((unsigned)h3 << 16);
      unsigned int pl0 = (unsigned)l0 | ((unsigned)l1 << 16), pl1 = (unsigned)l2 | ((unsigned)l3 << 16);
      int off = lc * 80 + (mw + lh * 4) * 2;
      *(u32x2*)(void*)(untbuf + off)        = (u32x2){ph0, ph1};
      *(u32x2*)(void*)(untbuf + 1280 + off) = (u32x2){pl0, pl1};
    }
    __syncthreads();   // barrier A: un^T visible; all stbuf reads done

    bf16x8 uh = *(const bf16x8*)(const void*)(untbuf + lc * 80 + lh * 16);
    bf16x8 ul = *(const bf16x8*)(const void*)(untbuf + 1280 + lc * 80 + lh * 16);
    accO = MFMA16(cAf, uh, accO);
    accO = MFMA16(cAf, ul, accO);
    o_out[rowElem + (size_t)(mw + lh*4 + 0) * 1024 + c0 + lc] = __float2bfloat16(accO[0]);
    o_out[rowElem + (size_t)(mw + lh*4 + 1) * 1024 + c0 + lc] = __float2bfloat16(accO[1]);
    o_out[rowElem + (size_t)(mw + lh*4 + 2) * 1024 + c0 + lc] = __float2bfloat16(accO[2]);
    o_out[rowElem + (size_t)(mw + lh*4 + 3) * 1024 + c0 + lc] = __float2bfloat16(accO[3]);

    // S += kT @ un (accumulator-resident; wave wv owns d rows wv*128..+128)
    #pragma unroll
    for (int mt = 0; mt < 8; mt++){
      Sf[mt] = MFMA16(kF[mt], uh, Sf[mt]);
      Sf[mt] = MFMA16(kF[mt], ul, Sf[mt]);
    }

    // write new S^T hi/lo
    #pragma unroll
    for (int mt = 0; mt < 8; mt++){
      const int dbase = wv * 128 + mt * 16 + lh * 4;
      float v0 = Sf[mt][0], v1 = Sf[mt][1], v2 = Sf[mt][2], v3 = Sf[mt][3];
      u16 h0 = f2bfu(v0), h1 = f2bfu(v1), h2 = f2bfu(v2), h3 = f2bfu(v3);
      u16 s0 = f2bfu(v0 - bfu2f(h0)), s1 = f2bfu(v1 - bfu2f(h1));
      u16 s2 = f2bfu(v2 - bfu2f(h2)), s3 = f2bfu(v3 - bfu2f(h3));
      int off = ((lc * 512 + dbase * 2) ^ ((lc & 7) << 4));
      *(u32x2*)(void*)(stbuf + off) =
          (u32x2){(unsigned)h0 | ((unsigned)h1 << 16), (unsigned)h2 | ((unsigned)h3 << 16)};
      *(u32x2*)(void*)(stbuf + 8192 + off) =
          (u32x2){(unsigned)s0 | ((unsigned)s1 << 16), (unsigned)s2 | ((unsigned)s3 << 16)};
    }
    if (ch < 127){
      cu0 = pu0; cu1 = pu1; cu2 = pu2; cu3 = pu3; cAf = pAf;
    }
    __syncthreads();   // barrier C: new S^T visible for next chunk
  }
}

// ---------------------------------------------------------------------------
// K6: o = mix*o + (1-mix)*v_token ; RMS-norm over dv=256 * norm_w -> bf16
// Vectorized: 8 slots of (tok,h) per block; 32 lanes x bf16x8 per slot.
// ---------------------------------------------------------------------------
__global__ __launch_bounds__(256) void postproc(
    const bf16* __restrict__ o_in, const bf16* __restrict__ v_tok,
    const float* __restrict__ mixb, const float* __restrict__ norm_w,
    bf16* __restrict__ onorm)
{
  const int tid = threadIdx.x;
  const int slot = tid >> 5, g = tid & 31;     // slot 0..7, lane-in-slot
  const int blk = blockIdx.x * 8 + slot;       // (tok*4 + h), < 65536
  const size_t base = (size_t)blk * 256 + g * 8;
  const u16* oin = (const u16*)o_in;
  const u16* vin = (const u16*)v_tok;
  bf16x8 ov8 = *(const bf16x8*)(const void*)(oin + base);
  bf16x8 vv8 = *(const bf16x8*)(const void*)(vin + base);
  float m = mixb[blk];
  float val[8];
  float ss = 0.f;
  #pragma unroll
  for (int e = 0; e < 8; e++){
    float v = m * bfu2f((u16)ov8[e]) + (1.f - m) * bfu2f((u16)vv8[e]);
    val[e] = v;
    ss += v * v;
  }
  #pragma unroll
  for (int off = 16; off; off >>= 1) ss += __shfl_down(ss, off, 32);
  ss = __shfl(ss, 0, 32);
  float r = rsqrtf(ss * (1.f / 256.f) + 1e-5f);
  const float4 nw0 = ((const float4*)norm_w)[g * 2];
  const float4 nw1 = ((const float4*)norm_w)[g * 2 + 1];
  const float nw[8] = {nw0.x, nw0.y, nw0.z, nw0.w, nw1.x, nw1.y, nw1.z, nw1.w};
  u16 o8[8];
  #pragma unroll
  for (int e = 0; e < 8; e++) o8[e] = f2bfu(val[e] * r * nw[e]);
  *(bf16x8*)(void*)((u16*)onorm + base) = *(bf16x8*)o8;
}

// ---------------------------------------------------------------------------
// Workspace budget (<= round-2-proven 239,599,616 bytes). Aliases:
//   xbf = b4 region ; wqb/wkb/wvb = front of b3 ; wob = kTg region (post-scan)
// ---------------------------------------------------------------------------
extern "C" void kernel_launch(void* const* d_in, const int* in_sizes, int n_in,
                              void* d_out, int out_size, void* d_ws, size_t ws_size,
                              hipStream_t stream)
{
  (void)in_sizes; (void)n_in; (void)out_size; (void)ws_size;
  const float* x     = (const float*)d_in[0];
  const float* Wq    = (const float*)d_in[1];
  const float* Wk    = (const float*)d_in[2];
  const float* Wv    = (const float*)d_in[3];
  const float* convq = (const float*)d_in[4];
  const float* convk = (const float*)d_in[5];
  const float* convv = (const float*)d_in[6];
  const float* Wb    = (const float*)d_in[7];
  const float* Wmix  = (const float*)d_in[8];
  const float* normw = (const float*)d_in[9];
  const float* Wo    = (const float*)d_in[10];
  float* out = (float*)d_out;

  char* wsb = (char*)d_ws;
  const size_t BIGB = (size_t)16777216 * 2;   // one bf16 [16384][1024] buffer
  bf16* b0 = (bf16*)(wsb + 0*BIGB);  // qlin -> later w
  bf16* b1 = (bf16*)(wsb + 1*BIGB);  // klin -> later o
  bf16* b2 = (bf16*)(wsb + 2*BIGB);  // vlin -> later u
  bf16* b3 = (bf16*)(wsb + 3*BIGB);  // (wq/wk/wv bf16) -> qc -> qn -> onorm
  bf16* b4 = (bf16*)(wsb + 4*BIGB);  // (x bf16) -> kc
  bf16* b5 = (bf16*)(wsb + 5*BIGB);  // vc (v_token, persistent)
  bf16*  Ab   = (bf16*) (wsb + 6*BIGB);                            // 4MiB
  float* beta = (float*)(wsb + 6*BIGB + 4194304);                  // 256KiB
  float* mixb = beta + 65536;                                      // 256KiB
  bf16*  kTg  = (bf16*) (wsb + 6*BIGB + 4194304 + 524288);         // 32MiB

  u16* xbf = (u16*)b4;
  u16* wqb = (u16*)b3;
  u16* wkb = wqb + (size_t)1024*1024;
  u16* wvb = wkb + (size_t)1024*1024;
  u16* wob = (u16*)kTg;

  cvt_bf16<<<8192, 256, 0, stream>>>(x, xbf, 2097152);
  cvt3_bf16<<<dim3(512, 3), 256, 0, stream>>>(Wq, Wk, Wv, wqb, wkb, wvb);

  gemm_bt<3, false><<<dim3(128, 8, 3), 256, 0, stream>>>(
      xbf, wqb, wkb, wvb, (void*)b0, (void*)b1, (void*)b2);
  small_proj<<<16384, 256, 0, stream>>>(x, Wb, Wmix, beta, mixb);
  conv_silu3<<<dim3(8192, 3), 256, 0, stream>>>(
      b0, b1, b2, convq, convk, convv, b3, b4, b5);
  chunk_prep<<<2048, 256, 0, stream>>>(b3, b4, b5, beta, b2, b0, Ab, kTg);
  hipFuncSetAttribute((const void*)scan_kernel,
                      hipFuncAttributeMaxDynamicSharedMemorySize, 18944);
  scan_kernel<<<256, 128, 18944, stream>>>((const u16*)b0, (const u16*)b3,
                                           (const u16*)b2, Ab, kTg, b1);
  cvt_bf16<<<512, 256, 0, stream>>>(Wo, wob, 131072);   // kTg dead after scan
  postproc  <<<8192, 256, 0, stream>>>(b1, b5, mixb, normw, b3);
  gemm_bt<1, true><<<dim3(128, 8, 1), 256, 0, stream>>>(
      (const u16*)b3, wob, wob, wob, (void*)out, (void*)out, (void*)out);
}

// Round 14
// 696.832 us; speedup vs baseline: 1.0917x; 1.0917x over previous
//
#include <hip/hip_runtime.h>
#include <hip/hip_bf16.h>

typedef __hip_bfloat16 bf16;
typedef unsigned short u16;
typedef __attribute__((ext_vector_type(4))) float f32x4;
typedef __attribute__((ext_vector_type(8))) short bf16x8;
typedef __attribute__((ext_vector_type(2))) unsigned int u32x2;

#define MFMA16(a, b, c) __builtin_amdgcn_mfma_f32_16x16x32_bf16((a), (b), (c), 0, 0, 0)

__device__ __forceinline__ float bfu2f(u16 u){
  return __uint_as_float(((unsigned int)u) << 16);
}
__device__ __forceinline__ u16 f2bfu(float x){
  return __builtin_bit_cast(u16, __float2bfloat16(x));
}
__device__ __forceinline__ void gload16(const void* g, const void* l){
  __builtin_amdgcn_global_load_lds(
      (const __attribute__((address_space(1))) unsigned int*)g,
      (__attribute__((address_space(3))) unsigned int*)l, 16, 0, 0);
}

// ---------------------------------------------------------------------------
// cvt: fp32 -> bf16, 8 elems/thread (single matrix)
// ---------------------------------------------------------------------------
__global__ __launch_bounds__(256) void cvt_bf16(
    const float* __restrict__ src, u16* __restrict__ dst, int n8)
{
  int i = blockIdx.x * 256 + threadIdx.x;
  if (i >= n8) return;
  const float4* s = (const float4*)src;
  float4 a = s[i * 2], b = s[i * 2 + 1];
  u16 o[8] = {f2bfu(a.x), f2bfu(a.y), f2bfu(a.z), f2bfu(a.w),
              f2bfu(b.x), f2bfu(b.y), f2bfu(b.z), f2bfu(b.w)};
  *(bf16x8*)(dst + (size_t)i * 8) = *(bf16x8*)o;
}

// cvt for the 3 projection weights in one launch (blockIdx.y selects)
__global__ __launch_bounds__(256) void cvt3_bf16(
    const float* __restrict__ s0, const float* __restrict__ s1, const float* __restrict__ s2,
    u16* __restrict__ d0, u16* __restrict__ d1, u16* __restrict__ d2)
{
  const float* s; u16* d;
  if (blockIdx.y == 0)      { s = s0; d = d0; }
  else if (blockIdx.y == 1) { s = s1; d = d1; }
  else                      { s = s2; d = d2; }
  int i = blockIdx.x * 256 + threadIdx.x;      // < 131072
  const float4* sp = (const float4*)s;
  float4 a = sp[i * 2], b = sp[i * 2 + 1];
  u16 o[8] = {f2bfu(a.x), f2bfu(a.y), f2bfu(a.z), f2bfu(a.w),
              f2bfu(b.x), f2bfu(b.y), f2bfu(b.z), f2bfu(b.w)};
  *(bf16x8*)(d + (size_t)i * 8) = *(bf16x8*)o;
}

// ---------------------------------------------------------------------------
// bf16 MFMA GEMM: C[M x 1024] = A[M x 1024] @ B^T (B stored [1024][1024] row=n)
// 128x128 tile, BK=64, 4 waves (2x2), 4x4 frags of 16x16x32.
// ---------------------------------------------------------------------------
template<int NMAT, bool F32OUT>
__global__ __launch_bounds__(256) void gemm_bt(
    const u16* __restrict__ A,
    const u16* __restrict__ B0, const u16* __restrict__ B1, const u16* __restrict__ B2,
    void* __restrict__ C0, void* __restrict__ C1, void* __restrict__ C2)
{
  const u16* B; void* C;
  if (NMAT == 1 || blockIdx.z == 0){ B = B0; C = C0; }
  else if (blockIdx.z == 1)        { B = B1; C = C1; }
  else                             { B = B2; C = C2; }
  __shared__ char lds[2][2][16384];   // [buf][A=0/B=1][128 rows * 128B]
  const int tid = threadIdx.x;
  const int lane = tid & 63, wv = tid >> 6;
  const int lc = lane & 15, lh = lane >> 4;
  const int wr = wv >> 1, wc = wv & 1;
  const int m0 = blockIdx.x * 128, n0 = blockIdx.y * 128;

  f32x4 acc[4][4];
  #pragma unroll
  for (int mt = 0; mt < 4; mt++)
    #pragma unroll
    for (int nt = 0; nt < 4; nt++) acc[mt][nt] = (f32x4){0.f, 0.f, 0.f, 0.f};

  auto stage = [&](int buf, int k0){
    #pragma unroll
    for (int c = 0; c < 4; c++){
      const int q = wv * 4096 + c * 1024;            // wave-uniform LDS base
      const int row = (q >> 7) + (lane >> 3);        // per-lane row
      const int slot = (lane & 7) ^ (row & 7);       // logical slot to fetch
      gload16(A + (size_t)(m0 + row) * 1024 + k0 + slot * 8, &lds[buf][0][q]);
      gload16(B + (size_t)(n0 + row) * 1024 + k0 + slot * 8, &lds[buf][1][q]);
    }
  };

  stage(0, 0);
  __syncthreads();
  int cur = 0;
  for (int t = 0; t < 16; t++){
    if (t < 15) stage(cur ^ 1, (t + 1) * 64);
    const char* Abuf = lds[cur][0];
    const char* Bbuf = lds[cur][1];
    #pragma unroll
    for (int kk = 0; kk < 2; kk++){
      bf16x8 af[4], bfr[4];
      #pragma unroll
      for (int mt = 0; mt < 4; mt++){
        int r = wr * 64 + mt * 16 + lc;
        int slot = (kk * 4 + lh) ^ (r & 7);
        af[mt] = *(const bf16x8*)(const void*)(Abuf + r * 128 + slot * 16);
      }
      #pragma unroll
      for (int nt = 0; nt < 4; nt++){
        int r = wc * 64 + nt * 16 + lc;
        int slot = (kk * 4 + lh) ^ (r & 7);
        bfr[nt] = *(const bf16x8*)(const void*)(Bbuf + r * 128 + slot * 16);
      }
      #pragma unroll
      for (int mt = 0; mt < 4; mt++)
        #pragma unroll
        for (int nt = 0; nt < 4; nt++)
          acc[mt][nt] = MFMA16(af[mt], bfr[nt], acc[mt][nt]);
    }
    __syncthreads();
    cur ^= 1;
  }

  #pragma unroll
  for (int mt = 0; mt < 4; mt++)
    #pragma unroll
    for (int nt = 0; nt < 4; nt++)
      #pragma unroll
      for (int rg = 0; rg < 4; rg++){
        int row = m0 + wr * 64 + mt * 16 + lh * 4 + rg;
        int col = n0 + wc * 64 + nt * 16 + lc;
        if (F32OUT) ((float*)C)[(size_t)row * 1024 + col] = acc[mt][nt][rg];
        else ((bf16*)C)[(size_t)row * 1024 + col] = __float2bfloat16(acc[mt][nt][rg]);
      }
}

// ---------------------------------------------------------------------------
// K2: beta = sigmoid(x@Wb^T) stored [b][h][l]; mix = sigmoid(x@Wmix^T) [tok][h]
// ---------------------------------------------------------------------------
__global__ __launch_bounds__(256) void small_proj(
    const float* __restrict__ x, const float* __restrict__ Wb,
    const float* __restrict__ Wmix, float* __restrict__ beta, float* __restrict__ mixb)
{
  const int tok = blockIdx.x;
  const int tid = threadIdx.x;
  __shared__ __align__(16) float xrow[1024];
  ((float4*)xrow)[tid] = ((const float4*)(x + (size_t)tok * 1024))[tid];
  __syncthreads();
  const int o = tid >> 5, g = tid & 31;
  const float* Wrow = (o < 4) ? (Wb + (size_t)o * 1024) : (Wmix + (size_t)(o - 4) * 1024);
  float p = 0.f;
  for (int e = g; e < 256; e += 32){
    float4 xv = ((const float4*)xrow)[e];
    float4 wv = ((const float4*)Wrow)[e];
    p += xv.x * wv.x + xv.y * wv.y + xv.z * wv.z + xv.w * wv.w;
  }
  for (int off = 16; off; off >>= 1) p += __shfl_down(p, off, 32);
  if (g == 0){
    float s = 1.f / (1.f + expf(-p));
    int b = tok >> 12, t = tok & 4095;
    if (o < 4) beta[((size_t)(b * 4 + o)) * 4096 + t] = s;
    else       mixb[(size_t)tok * 4 + (o - 4)] = s;
  }
}

// ---------------------------------------------------------------------------
// K3: causal depthwise conv (K=4) + silu, vectorized bf16x8 (8 channels/thread)
// ---------------------------------------------------------------------------
__global__ __launch_bounds__(256) void conv_silu3(
    const bf16* __restrict__ in0, const bf16* __restrict__ in1, const bf16* __restrict__ in2,
    const float* __restrict__ w0, const float* __restrict__ w1, const float* __restrict__ w2,
    bf16* __restrict__ o0, bf16* __restrict__ o1, bf16* __restrict__ o2)
{
  const bf16* in; const float* wc; bf16* out;
  if (blockIdx.y == 0)      { in = in0; wc = w0; out = o0; }
  else if (blockIdx.y == 1) { in = in1; wc = w1; out = o1; }
  else                      { in = in2; wc = w2; out = o2; }
  const int idx8 = blockIdx.x * 256 + threadIdx.x;   // < 2097152
  const int c8 = (idx8 & 127) * 8;
  const int tt = idx8 >> 7;            // b*4096 + t
  const int t  = tt & 4095;
  const u16* inu = (const u16*)in;
  const size_t base = (size_t)tt * 1024 + c8;
  bf16x8 zv = {0, 0, 0, 0, 0, 0, 0, 0};
  bf16x8 x3 = *(const bf16x8*)(const void*)(inu + base);
  bf16x8 x2 = (t >= 1) ? *(const bf16x8*)(const void*)(inu + base - 1024) : zv;
  bf16x8 x1 = (t >= 2) ? *(const bf16x8*)(const void*)(inu + base - 2048) : zv;
  bf16x8 x0 = (t >= 3) ? *(const bf16x8*)(const void*)(inu + base - 3072) : zv;
  u16 o8[8];
  #pragma unroll
  for (int e = 0; e < 8; e++){
    const float4 w4 = ((const float4*)wc)[c8 + e];
    float s = w4.w * bfu2f((u16)x3[e]) + w4.z * bfu2f((u16)x2[e])
            + w4.y * bfu2f((u16)x1[e]) + w4.x * bfu2f((u16)x0[e]);
    s = s / (1.f + expf(-s));
    o8[e] = f2bfu(s);
  }
  *(bf16x8*)(void*)((u16*)out + base) = *(bf16x8*)o8;
}

// ---------------------------------------------------------------------------
// K4: per-chunk prep, MFMA version (unchanged).
// ---------------------------------------------------------------------------
__global__ __launch_bounds__(256, 2) void chunk_prep(
    bf16* __restrict__ qc, const bf16* __restrict__ kc, const bf16* __restrict__ vc,
    const float* __restrict__ beta,
    bf16* __restrict__ u_out, bf16* __restrict__ w_out,
    bf16* __restrict__ Ab, bf16* __restrict__ kTg)
{
  __shared__ char kS[16384], qS[16384];       // [32][256] bf16, row-swizzled
  __shared__ float att[1056];                 // [32][33] fp32
  __shared__ char Th[2048], Tl[2048];         // T hi/lo [32]x64B, group-swizzled
  __shared__ char vTh[8192], vTl[8192];       // vb^T half [128]x64B hi/lo
  __shared__ char wTh[8192], wTl[8192];       // kb^T half
  __shared__ float rnk_s[32], rnq_s[32], bvec[32];

  const int g = blockIdx.x;
  const int ch = g & 127, h = (g >> 7) & 3, b = g >> 9;
  const int tid = threadIdx.x;
  const int l = tid & 63, wv = tid >> 6;
  const int lc = l & 15, lh = l >> 4;
  const int i = tid >> 3, s = tid & 7;        // row, 32-col slice
  const size_t rowbase = ((size_t)(b * 4096 + ch * 32)) * 1024 + (size_t)h * 256;
  const u16* kcu = (const u16*)kc;
  const u16* qcu = (const u16*)qc;
  const u16* vcu = (const u16*)vc;

  // ---- P1: load + row sum-of-squares ----
  bf16x8 kr[4], qr[4], vr[4];
  float ssk = 0.f, ssq = 0.f;
  #pragma unroll
  for (int j4 = 0; j4 < 4; j4++){
    size_t eo = rowbase + (size_t)i * 1024 + s * 32 + j4 * 8;
    kr[j4] = *(const bf16x8*)(const void*)(kcu + eo);
    qr[j4] = *(const bf16x8*)(const void*)(qcu + eo);
    vr[j4] = *(const bf16x8*)(const void*)(vcu + eo);
    #pragma unroll
    for (int e = 0; e < 8; e++){
      float kv = bfu2f((u16)kr[j4][e]); ssk += kv * kv;
      float qv = bfu2f((u16)qr[j4][e]); ssq += qv * qv;
    }
  }
  #pragma unroll
  for (int off = 1; off < 8; off <<= 1){
    ssk += __shfl_xor(ssk, off, 64);
    ssq += __shfl_xor(ssq, off, 64);
  }
  if (s == 0){
    rnk_s[i] = 1.0f / sqrtf(ssk + 1e-6f);
    rnq_s[i] = 1.0f / sqrtf(ssq + 1e-6f);
  }
  if (tid < 32) bvec[tid] = beta[((size_t)(b * 4 + h)) * 4096 + ch * 32 + tid];
  __syncthreads();

  // ---- P2: normalize; stage kS/qS; write qn global; vT/kbT half 0 ----
  const float rk = rnk_s[i], rq = rnq_s[i], bi = bvec[i];
  #pragma unroll
  for (int j4 = 0; j4 < 4; j4++){
    u16 kn8[8], qn8[8];
    #pragma unroll
    for (int e = 0; e < 8; e++){
      kn8[e] = f2bfu(bfu2f((u16)kr[j4][e]) * rk);
      qn8[e] = f2bfu(bfu2f((u16)qr[j4][e]) * rq);
    }
    int byt = (i * 512 + s * 64 + j4 * 16) ^ ((i & 7) << 4);
    *(bf16x8*)(void*)(kS + byt) = *(bf16x8*)kn8;
    *(bf16x8*)(void*)(qS + byt) = *(bf16x8*)qn8;
    *(bf16x8*)(void*)((u16*)qc + rowbase + (size_t)i * 1024 + s * 32 + j4 * 8) = *(bf16x8*)kn8 * 0 + *(bf16x8*)qn8;
  }
  if ((s >> 2) == 0){
    #pragma unroll
    for (int j4 = 0; j4 < 4; j4++)
      #pragma unroll
      for (int e = 0; e < 8; e++){
        int dl = (s & 3) * 32 + j4 * 8 + e;
        float vb = bfu2f((u16)vr[j4][e]) * bi;
        float kb = bfu2f((u16)kr[j4][e]) * rk * bi;
        u16 vh = f2bfu(vb), kh = f2bfu(kb);
        u16 vlo = f2bfu(vb - bfu2f(vh)), klo = f2bfu(kb - bfu2f(kh));
        int byt = dl * 64 + (((i >> 3) ^ ((dl >> 1) & 3)) << 4) + (i & 7) * 2;
        *(u16*)(vTh + byt) = vh; *(u16*)(vTl + byt) = vlo;
        *(u16*)(wTh + byt) = kh; *(u16*)(wTl + byt) = klo;
      }
  }
  __syncthreads();

  // ---- P3: L & A quadrants via MFMA; kTg transpose-out ----
  {
    const int mq = wv >> 1, nq = wv & 1;
    const int rowA = mq * 16 + lc, rowB = nq * 16 + lc;
    const int swA = (rowA & 7) << 4, swB = (rowB & 7) << 4;
    f32x4 accL = (f32x4){0.f, 0.f, 0.f, 0.f};
    f32x4 accA = (f32x4){0.f, 0.f, 0.f, 0.f};
    #pragma unroll
    for (int kt = 0; kt < 8; kt++){
      bf16x8 af  = *(const bf16x8*)(const void*)(kS + ((rowA * 512 + kt * 64 + lh * 16) ^ swA));
      bf16x8 bf_ = *(const bf16x8*)(const void*)(kS + ((rowB * 512 + kt * 64 + lh * 16) ^ swB));
      bf16x8 aq  = *(const bf16x8*)(const void*)(qS + ((rowA * 512 + kt * 64 + lh * 16) ^ swA));
      accL = MFMA16(af, bf_, accL);
      accA = MFMA16(aq, bf_, accA);
    }
    #pragma unroll
    for (int r = 0; r < 4; r++){
      int rr = mq * 16 + lh * 4 + r, cc = nq * 16 + lc;
      att[rr * 33 + cc] = (cc < rr) ? (-bvec[rr] * accL[r]) : 0.f;
      float av = (cc <= rr) ? accA[r] : 0.f;
      ((u16*)Ab)[(size_t)g * 1024 + rr * 32 + cc] = f2bfu(av);
    }
  }
  {
    u16 tmp[32];
    #pragma unroll
    for (int i2 = 0; i2 < 32; i2++)
      tmp[i2] = *(const u16*)(kS + ((i2 * 512 + tid * 2) ^ ((i2 & 7) << 4)));
    #pragma unroll
    for (int j4 = 0; j4 < 4; j4++)
      *(bf16x8*)(void*)((u16*)kTg + (size_t)g * 8192 + tid * 32 + j4 * 8) = *(bf16x8*)(tmp + j4 * 8);
  }
  __syncthreads();

  // ---- P4: wave-0 fp32 forward substitution (barrier-free in-wave) ----
  if (wv == 0 && l < 32){
    for (int ii = 1; ii < 32; ii++){
      float upd = 0.f;
      for (int m = 0; m < ii; m++)
        upd += att[ii * 33 + m] * att[m * 33 + l];
      att[ii * 33 + l] += upd;
    }
    att[l * 33 + l] = 1.0f;   // T = subst(L) + I
  }
  __syncthreads();

  // ---- P5: T -> hi/lo bf16 ----
  #pragma unroll
  for (int z = 0; z < 4; z++){
    int e = tid * 4 + z;
    int row = e >> 5, col = e & 31;
    float f = att[row * 33 + col];
    u16 hh = f2bfu(f), llo = f2bfu(f - bfu2f(hh));
    int byt = row * 64 + ((((col >> 3)) ^ ((row >> 1) & 3)) << 4) + (col & 7) * 2;
    *(u16*)(Th + byt) = hh; *(u16*)(Tl + byt) = llo;
  }
  __syncthreads();

  // ---- P6/P8: u = T@vb, w = T@kb (3-term hi/lo), two dv halves ----
  {
    const int mq = wv >> 1, nsel = wv & 1;
    const int rowA = mq * 16 + lc;
    const int sa = (lh ^ ((rowA >> 1) & 3)) << 4;
    bf16x8 ta = *(const bf16x8*)(const void*)(Th + rowA * 64 + sa);
    bf16x8 tl = *(const bf16x8*)(const void*)(Tl + rowA * 64 + sa);
    #pragma unroll
    for (int half = 0; half < 2; half++){
      if (half == 1){
        __syncthreads();            // all half-0 reads done
        if ((s >> 2) == 1){         // P7: stage half 1
          #pragma unroll
          for (int j4 = 0; j4 < 4; j4++)
            #pragma unroll
            for (int e = 0; e < 8; e++){
              int dl = (s & 3) * 32 + j4 * 8 + e;
              float vb = bfu2f((u16)vr[j4][e]) * bi;
              float kb = bfu2f((u16)kr[j4][e]) * rk * bi;
              u16 vh = f2bfu(vb), kh = f2bfu(kb);
              u16 vlo = f2bfu(vb - bfu2f(vh)), klo = f2bfu(kb - bfu2f(kh));
              int byt = dl * 64 + (((i >> 3) ^ ((dl >> 1) & 3)) << 4) + (i & 7) * 2;
              *(u16*)(vTh + byt) = vh; *(u16*)(vTl + byt) = vlo;
              *(u16*)(wTh + byt) = kh; *(u16*)(wTl + byt) = klo;
            }
        }
        __syncthreads();
      }
      #pragma unroll
      for (int nt = 0; nt < 4; nt++){
        int nl = nsel * 64 + nt * 16;
        int rowB = nl + lc;
        int sb = (lh ^ ((rowB >> 1) & 3)) << 4;
        bf16x8 bh_ = *(const bf16x8*)(const void*)(vTh + rowB * 64 + sb);
        bf16x8 bl_ = *(const bf16x8*)(const void*)(vTl + rowB * 64 + sb);
        f32x4 aU = (f32x4){0.f, 0.f, 0.f, 0.f};
        aU = MFMA16(ta, bh_, aU);
        aU = MFMA16(ta, bl_, aU);
        aU = MFMA16(tl, bh_, aU);
        bf16x8 wh_ = *(const bf16x8*)(const void*)(wTh + rowB * 64 + sb);
        bf16x8 wl_ = *(const bf16x8*)(const void*)(wTl + rowB * 64 + sb);
        f32x4 aW = (f32x4){0.f, 0.f, 0.f, 0.f};
        aW = MFMA16(ta, wh_, aW);
        aW = MFMA16(ta, wl_, aW);
        aW = MFMA16(tl, wh_, aW);
        #pragma unroll
        for (int r = 0; r < 4; r++){
          int row = mq * 16 + lh * 4 + r, col = half * 128 + nl + lc;
          ((u16*)u_out)[rowbase + (size_t)row * 1024 + col] = f2bfu(aU[r]);
          ((u16*)w_out)[rowbase + (size_t)row * 1024 + col] = f2bfu(aW[r]);
        }
      }
    }
  }
}

// ---------------------------------------------------------------------------
// K5: sequential chunk scan, round-14: r12 structure with w/q A-fragments
// prefetched into REGISTERS one chunk ahead (restores r12's prefetch distance
// that r13 lost, while keeping r13's LDS-traffic elimination). Per wave:
// cw/cq[8] hold current chunk's fragments; pw/pq[8] are loaded at the top of
// each iteration for chunk+1 (>=600cy before the barrier-A vmcnt drain).
// No wqbuf LDS, no global_load_lds staging, no aw/aq ds_reads.
// kF direct from global (r9-proven). Arithmetic bit-identical to r12.
// LDS: S^T hi/lo 16K + un^T 2.5K = 18944 B.
// ---------------------------------------------------------------------------
__global__ __launch_bounds__(128, 1) void scan_kernel(
    const u16* __restrict__ w_in, const u16* __restrict__ qn,
    const u16* __restrict__ u_in, const bf16* __restrict__ Ab,
    const bf16* __restrict__ kTg, bf16* __restrict__ o_out)
{
  extern __shared__ char smem[];
  char* stbuf  = smem;               // S^T hi 8K | lo 8K ([16 c][512B]) swizzled
  char* untbuf = smem + 16384;       // un^T hi 1280 | lo 1280 ([16 c][80B])

  const int tid = threadIdx.x;                 // 0..127
  const int l = tid & 63, wv = tid >> 6;       // wv 0..1
  const int lc = l & 15, lh = l >> 4;
  const int wg = blockIdx.x;
  const int bh = (wg & 7) * 2 + ((wg >> 3) & 1);  // all 16 vb of a bh on one XCD
  const int vb = wg >> 4;                      // 0..15
  const int h = bh & 3, b = bh >> 2;
  const int c0 = vb * 16;
  const int mw = wv * 16;                      // wave's un-row block

  f32x4 Sf[8];
  #pragma unroll
  for (int mt = 0; mt < 8; mt++) Sf[mt] = (f32x4){0.f, 0.f, 0.f, 0.f};

  const size_t bhElem = (size_t)b * 4096 * 1024 + (size_t)h * 256;
  const u16* kTu = (const u16*)kTg;

  // prologue: zero S^T; load chunk-0 w/q frags + u/A frags
  for (int e = tid; e < 4096; e += 128) ((unsigned int*)(void*)stbuf)[e] = 0u;
  bf16x8 cw[8], cq[8];
  {
    const size_t rowOff = bhElem + (size_t)(mw + lc) * 1024 + lh * 8;
    #pragma unroll
    for (int kt = 0; kt < 8; kt++){
      cw[kt] = *(const bf16x8*)(const void*)(w_in + rowOff + kt * 32);
      cq[kt] = *(const bf16x8*)(const void*)(qn + rowOff + kt * 32);
    }
  }
  u16 cu0 = u_in[bhElem + (size_t)(mw + lh*4 + 0) * 1024 + c0 + lc];
  u16 cu1 = u_in[bhElem + (size_t)(mw + lh*4 + 1) * 1024 + c0 + lc];
  u16 cu2 = u_in[bhElem + (size_t)(mw + lh*4 + 2) * 1024 + c0 + lc];
  u16 cu3 = u_in[bhElem + (size_t)(mw + lh*4 + 3) * 1024 + c0 + lc];
  bf16x8 cAf = *(const bf16x8*)(const void*)(Ab + (size_t)(bh * 128) * 1024 + (mw + lc) * 32 + lh * 8);
  __syncthreads();

  for (int ch = 0; ch < 128; ch++){
    const size_t rowElem = bhElem + (size_t)ch * 32768;
    // prefetch chunk+1 w/q into registers (consumed NEXT iteration)
    bf16x8 pw[8], pq[8];
    u16 pu0, pu1, pu2, pu3; bf16x8 pAf;
    if (ch < 127){
      const size_t rowN = rowElem + 32768;
      const size_t rowOffN = rowN + (size_t)(mw + lc) * 1024 + lh * 8;
      #pragma unroll
      for (int kt = 0; kt < 8; kt++){
        pw[kt] = *(const bf16x8*)(const void*)(w_in + rowOffN + kt * 32);
        pq[kt] = *(const bf16x8*)(const void*)(qn + rowOffN + kt * 32);
      }
      pu0 = u_in[rowN + (size_t)(mw + lh*4 + 0) * 1024 + c0 + lc];
      pu1 = u_in[rowN + (size_t)(mw + lh*4 + 1) * 1024 + c0 + lc];
      pu2 = u_in[rowN + (size_t)(mw + lh*4 + 2) * 1024 + c0 + lc];
      pu3 = u_in[rowN + (size_t)(mw + lh*4 + 3) * 1024 + c0 + lc];
      pAf = *(const bf16x8*)(const void*)(Ab + (size_t)(bh * 128 + ch + 1) * 1024 + (mw + lc) * 32 + lh * 8);
    }
    // current-chunk kT fragments (consumed after barrier A's vmcnt drain)
    bf16x8 kF[8];
    {
      const size_t ktCur = (size_t)(bh * 128 + ch) * 8192;
      #pragma unroll
      for (int mt = 0; mt < 8; mt++){
        int rowK = wv * 128 + mt * 16 + lc;
        kF[mt] = *(const bf16x8*)(const void*)(kTu + ktCur + (size_t)rowK * 32 + lh * 8);
      }
    }

    // fused phase: accU = w@S, accO = q@S (old S), even/odd-kt split chains;
    // A-operands straight from registers (cw/cq), S^T from LDS.
    f32x4 aU0 = (f32x4){0.f,0.f,0.f,0.f}, aU1 = (f32x4){0.f,0.f,0.f,0.f};
    f32x4 aO0 = (f32x4){0.f,0.f,0.f,0.f}, aO1 = (f32x4){0.f,0.f,0.f,0.f};
    {
      const int swS = (lc & 7) << 4;
      #pragma unroll
      for (int kt = 0; kt < 8; kt++){
        const int kb = kt * 64 + lh * 16;
        bf16x8 sh = *(const bf16x8*)(const void*)(stbuf + ((lc * 512 + kb) ^ swS));
        bf16x8 sl = *(const bf16x8*)(const void*)(stbuf + 8192 + ((lc * 512 + kb) ^ swS));
        if (kt & 1){
          aU1 = MFMA16(cw[kt], sh, aU1);
          aU1 = MFMA16(cw[kt], sl, aU1);
          aO1 = MFMA16(cq[kt], sh, aO1);
          aO1 = MFMA16(cq[kt], sl, aO1);
        } else {
          aU0 = MFMA16(cw[kt], sh, aU0);
          aU0 = MFMA16(cw[kt], sl, aU0);
          aO0 = MFMA16(cq[kt], sh, aO0);
          aO0 = MFMA16(cq[kt], sl, aO0);
        }
      }
    }
    f32x4 accO = aO0 + aO1;
    {
      f32x4 accU = aU0 + aU1;
      float v0 = bfu2f(cu0) - accU[0];
      float v1 = bfu2f(cu1) - accU[1];
      float v2 = bfu2f(cu2) - accU[2];
      float v3 = bfu2f(cu3) - accU[3];
      u16 h0 = f2bfu(v0), h1 = f2bfu(v1), h2 = f2bfu(v2), h3 = f2bfu(v3);
      u16 l0 = f2bfu(v0 - bfu2f(h0)), l1 = f2bfu(v1 - bfu2f(h1));
      u16 l2 = f2bfu(v2 - bfu2f(h2)), l3 = f2bfu(v3 - bfu2f(h3));
      unsigned int ph0 = (unsigned)h0 | ((unsigned)h1 << 16), ph1 = (unsigned)h2 | ((unsigned)h3 << 16);
      unsigned int pl0 = (unsigned)l0 | ((unsigned)l1 << 16), pl1 = (unsigned)l2 | ((unsigned)l3 << 16);
      int off = lc * 80 + (mw + lh * 4) * 2;
      *(u32x2*)(void*)(untbuf + off)        = (u32x2){ph0, ph1};
      *(u32x2*)(void*)(untbuf + 1280 + off) = (u32x2){pl0, pl1};
    }
    __syncthreads();   // barrier A: un^T visible; all stbuf reads done

    bf16x8 uh = *(const bf16x8*)(const void*)(untbuf + lc * 80 + lh * 16);
    bf16x8 ul = *(const bf16x8*)(const void*)(untbuf + 1280 + lc * 80 + lh * 16);
    accO = MFMA16(cAf, uh, accO);
    accO = MFMA16(cAf, ul, accO);
    o_out[rowElem + (size_t)(mw + lh*4 + 0) * 1024 + c0 + lc] = __float2bfloat16(accO[0]);
    o_out[rowElem + (size_t)(mw + lh*4 + 1) * 1024 + c0 + lc] = __float2bfloat16(accO[1]);
    o_out[rowElem + (size_t)(mw + lh*4 + 2) * 1024 + c0 + lc] = __float2bfloat16(accO[2]);
    o_out[rowElem + (size_t)(mw + lh*4 + 3) * 1024 + c0 + lc] = __float2bfloat16(accO[3]);

    // S += kT @ un (accumulator-resident; wave wv owns d rows wv*128..+128)
    #pragma unroll
    for (int mt = 0; mt < 8; mt++){
      Sf[mt] = MFMA16(kF[mt], uh, Sf[mt]);
      Sf[mt] = MFMA16(kF[mt], ul, Sf[mt]);
    }

    // write new S^T hi/lo
    #pragma unroll
    for (int mt = 0; mt < 8; mt++){
      const int dbase = wv * 128 + mt * 16 + lh * 4;
      float v0 = Sf[mt][0], v1 = Sf[mt][1], v2 = Sf[mt][2], v3 = Sf[mt][3];
      u16 h0 = f2bfu(v0), h1 = f2bfu(v1), h2 = f2bfu(v2), h3 = f2bfu(v3);
      u16 s0 = f2bfu(v0 - bfu2f(h0)), s1 = f2bfu(v1 - bfu2f(h1));
      u16 s2 = f2bfu(v2 - bfu2f(h2)), s3 = f2bfu(v3 - bfu2f(h3));
      int off = ((lc * 512 + dbase * 2) ^ ((lc & 7) << 4));
      *(u32x2*)(void*)(stbuf + off) =
          (u32x2){(unsigned)h0 | ((unsigned)h1 << 16), (unsigned)h2 | ((unsigned)h3 << 16)};
      *(u32x2*)(void*)(stbuf + 8192 + off) =
          (u32x2){(unsigned)s0 | ((unsigned)s1 << 16), (unsigned)s2 | ((unsigned)s3 << 16)};
    }
    if (ch < 127){
      #pragma unroll
      for (int kt = 0; kt < 8; kt++){ cw[kt] = pw[kt]; cq[kt] = pq[kt]; }
      cu0 = pu0; cu1 = pu1; cu2 = pu2; cu3 = pu3; cAf = pAf;
    }
    __syncthreads();   // barrier C: new S^T visible for next chunk
  }
}

// ---------------------------------------------------------------------------
// K6: o = mix*o + (1-mix)*v_token ; RMS-norm over dv=256 * norm_w -> bf16
// Vectorized: 8 slots of (tok,h) per block; 32 lanes x bf16x8 per slot.
// ---------------------------------------------------------------------------
__global__ __launch_bounds__(256) void postproc(
    const bf16* __restrict__ o_in, const bf16* __restrict__ v_tok,
    const float* __restrict__ mixb, const float* __restrict__ norm_w,
    bf16* __restrict__ onorm)
{
  const int tid = threadIdx.x;
  const int slot = tid >> 5, g = tid & 31;     // slot 0..7, lane-in-slot
  const int blk = blockIdx.x * 8 + slot;       // (tok*4 + h), < 65536
  const size_t base = (size_t)blk * 256 + g * 8;
  const u16* oin = (const u16*)o_in;
  const u16* vin = (const u16*)v_tok;
  bf16x8 ov8 = *(const bf16x8*)(const void*)(oin + base);
  bf16x8 vv8 = *(const bf16x8*)(const void*)(vin + base);
  float m = mixb[blk];
  float val[8];
  float ss = 0.f;
  #pragma unroll
  for (int e = 0; e < 8; e++){
    float v = m * bfu2f((u16)ov8[e]) + (1.f - m) * bfu2f((u16)vv8[e]);
    val[e] = v;
    ss += v * v;
  }
  #pragma unroll
  for (int off = 16; off; off >>= 1) ss += __shfl_down(ss, off, 32);
  ss = __shfl(ss, 0, 32);
  float r = rsqrtf(ss * (1.f / 256.f) + 1e-5f);
  const float4 nw0 = ((const float4*)norm_w)[g * 2];
  const float4 nw1 = ((const float4*)norm_w)[g * 2 + 1];
  const float nw[8] = {nw0.x, nw0.y, nw0.z, nw0.w, nw1.x, nw1.y, nw1.z, nw1.w};
  u16 o8[8];
  #pragma unroll
  for (int e = 0; e < 8; e++) o8[e] = f2bfu(val[e] * r * nw[e]);
  *(bf16x8*)(void*)((u16*)onorm + base) = *(bf16x8*)o8;
}

// ---------------------------------------------------------------------------
// Workspace budget (<= round-2-proven 239,599,616 bytes). Aliases:
//   xbf = b4 region ; wqb/wkb/wvb = front of b3 ; wob = kTg region (post-scan)
// ---------------------------------------------------------------------------
extern "C" void kernel_launch(void* const* d_in, const int* in_sizes, int n_in,
                              void* d_out, int out_size, void* d_ws, size_t ws_size,
                              hipStream_t stream)
{
  (void)in_sizes; (void)n_in; (void)out_size; (void)ws_size;
  const float* x     = (const float*)d_in[0];
  const float* Wq    = (const float*)d_in[1];
  const float* Wk    = (const float*)d_in[2];
  const float* Wv    = (const float*)d_in[3];
  const float* convq = (const float*)d_in[4];
  const float* convk = (const float*)d_in[5];
  const float* convv = (const float*)d_in[6];
  const float* Wb    = (const float*)d_in[7];
  const float* Wmix  = (const float*)d_in[8];
  const float* normw = (const float*)d_in[9];
  const float* Wo    = (const float*)d_in[10];
  float* out = (float*)d_out;

  char* wsb = (char*)d_ws;
  const size_t BIGB = (size_t)16777216 * 2;   // one bf16 [16384][1024] buffer
  bf16* b0 = (bf16*)(wsb + 0*BIGB);  // qlin -> later w
  bf16* b1 = (bf16*)(wsb + 1*BIGB);  // klin -> later o
  bf16* b2 = (bf16*)(wsb + 2*BIGB);  // vlin -> later u
  bf16* b3 = (bf16*)(wsb + 3*BIGB);  // (wq/wk/wv bf16) -> qc -> qn -> onorm
  bf16* b4 = (bf16*)(wsb + 4*BIGB);  // (x bf16) -> kc
  bf16* b5 = (bf16*)(wsb + 5*BIGB);  // vc (v_token, persistent)
  bf16*  Ab   = (bf16*) (wsb + 6*BIGB);                            // 4MiB
  float* beta = (float*)(wsb + 6*BIGB + 4194304);                  // 256KiB
  float* mixb = beta + 65536;                                      // 256KiB
  bf16*  kTg  = (bf16*) (wsb + 6*BIGB + 4194304 + 524288);         // 32MiB

  u16* xbf = (u16*)b4;
  u16* wqb = (u16*)b3;
  u16* wkb = wqb + (size_t)1024*1024;
  u16* wvb = wkb + (size_t)1024*1024;
  u16* wob = (u16*)kTg;

  cvt_bf16<<<8192, 256, 0, stream>>>(x, xbf, 2097152);
  cvt3_bf16<<<dim3(512, 3), 256, 0, stream>>>(Wq, Wk, Wv, wqb, wkb, wvb);

  gemm_bt<3, false><<<dim3(128, 8, 3), 256, 0, stream>>>(
      xbf, wqb, wkb, wvb, (void*)b0, (void*)b1, (void*)b2);
  small_proj<<<16384, 256, 0, stream>>>(x, Wb, Wmix, beta, mixb);
  conv_silu3<<<dim3(8192, 3), 256, 0, stream>>>(
      b0, b1, b2, convq, convk, convv, b3, b4, b5);
  chunk_prep<<<2048, 256, 0, stream>>>(b3, b4, b5, beta, b2, b0, Ab, kTg);
  hipFuncSetAttribute((const void*)scan_kernel,
                      hipFuncAttributeMaxDynamicSharedMemorySize, 18944);
  scan_kernel<<<256, 128, 18944, stream>>>((const u16*)b0, (const u16*)b3,
                                           (const u16*)b2, Ab, kTg, b1);
  cvt_bf16<<<512, 256, 0, stream>>>(Wo, wob, 131072);   // kTg dead after scan
  postproc  <<<8192, 256, 0, stream>>>(b1, b5, mixb, normw, b3);
  gemm_bt<1, true><<<dim3(128, 8, 1), 256, 0, stream>>>(
      (const u16*)b3, wob, wob, wob, (void*)out, (void*)out, (void*)out);
}

// Round 15
// 626.204 us; speedup vs baseline: 1.2148x; 1.1128x over previous
//
#include <hip/hip_runtime.h>
#include <hip/hip_bf16.h>

typedef __hip_bfloat16 bf16;
typedef unsigned short u16;
typedef __attribute__((ext_vector_type(4))) float f32x4;
typedef __attribute__((ext_vector_type(8))) short bf16x8;
typedef __attribute__((ext_vector_type(2))) unsigned int u32x2;

#define MFMA16(a, b, c) __builtin_amdgcn_mfma_f32_16x16x32_bf16((a), (b), (c), 0, 0, 0)

__device__ __forceinline__ float bfu2f(u16 u){
  return __uint_as_float(((unsigned int)u) << 16);
}
__device__ __forceinline__ u16 f2bfu(float x){
  return __builtin_bit_cast(u16, __float2bfloat16(x));
}
__device__ __forceinline__ void gload16(const void* g, const void* l){
  __builtin_amdgcn_global_load_lds(
      (const __attribute__((address_space(1))) unsigned int*)g,
      (__attribute__((address_space(3))) unsigned int*)l, 16, 0, 0);
}

// ---------------------------------------------------------------------------
// cvt: fp32 -> bf16, 8 elems/thread (single matrix)
// ---------------------------------------------------------------------------
__global__ __launch_bounds__(256) void cvt_bf16(
    const float* __restrict__ src, u16* __restrict__ dst, int n8)
{
  int i = blockIdx.x * 256 + threadIdx.x;
  if (i >= n8) return;
  const float4* s = (const float4*)src;
  float4 a = s[i * 2], b = s[i * 2 + 1];
  u16 o[8] = {f2bfu(a.x), f2bfu(a.y), f2bfu(a.z), f2bfu(a.w),
              f2bfu(b.x), f2bfu(b.y), f2bfu(b.z), f2bfu(b.w)};
  *(bf16x8*)(dst + (size_t)i * 8) = *(bf16x8*)o;
}

// cvt for the 3 projection weights in one launch (blockIdx.y selects)
__global__ __launch_bounds__(256) void cvt3_bf16(
    const float* __restrict__ s0, const float* __restrict__ s1, const float* __restrict__ s2,
    u16* __restrict__ d0, u16* __restrict__ d1, u16* __restrict__ d2)
{
  const float* s; u16* d;
  if (blockIdx.y == 0)      { s = s0; d = d0; }
  else if (blockIdx.y == 1) { s = s1; d = d1; }
  else                      { s = s2; d = d2; }
  int i = blockIdx.x * 256 + threadIdx.x;      // < 131072
  const float4* sp = (const float4*)s;
  float4 a = sp[i * 2], b = sp[i * 2 + 1];
  u16 o[8] = {f2bfu(a.x), f2bfu(a.y), f2bfu(a.z), f2bfu(a.w),
              f2bfu(b.x), f2bfu(b.y), f2bfu(b.z), f2bfu(b.w)};
  *(bf16x8*)(d + (size_t)i * 8) = *(bf16x8*)o;
}

// ---------------------------------------------------------------------------
// bf16 MFMA GEMM: C[M x 1024] = A[M x 1024] @ B^T (B stored [1024][1024] row=n)
// 128x128 tile, BK=64, 4 waves (2x2), 4x4 frags of 16x16x32.
// Round-15: XCD/L2-aware block remap — lin = bx + 128*by; xcd = lin&7 gets 16
// contiguous m-panels, each with its 8 n-tiles adjacent -> A-panel fetched
// from HBM once and L2-hit 7x (was: 8x HBM re-fetch, ~768MB for the 3 projs).
// Bijective: m0idx = xcd*16 + (lin>>6) in [0,128), n0idx = (lin>>3)&7.
// ---------------------------------------------------------------------------
template<int NMAT, bool F32OUT>
__global__ __launch_bounds__(256) void gemm_bt(
    const u16* __restrict__ A,
    const u16* __restrict__ B0, const u16* __restrict__ B1, const u16* __restrict__ B2,
    void* __restrict__ C0, void* __restrict__ C1, void* __restrict__ C2)
{
  const u16* B; void* C;
  if (NMAT == 1 || blockIdx.z == 0){ B = B0; C = C0; }
  else if (blockIdx.z == 1)        { B = B1; C = C1; }
  else                             { B = B2; C = C2; }
  __shared__ char lds[2][2][16384];   // [buf][A=0/B=1][128 rows * 128B]
  const int tid = threadIdx.x;
  const int lane = tid & 63, wv = tid >> 6;
  const int lc = lane & 15, lh = lane >> 4;
  const int wr = wv >> 1, wc = wv & 1;
  const int lin = blockIdx.x + (blockIdx.y << 7);     // 0..1023, x fastest
  const int m0 = ((lin & 7) * 16 + (lin >> 6)) * 128; // 16 m-panels per XCD
  const int n0 = ((lin >> 3) & 7) * 128;              // n-tiles adjacent per m

  f32x4 acc[4][4];
  #pragma unroll
  for (int mt = 0; mt < 4; mt++)
    #pragma unroll
    for (int nt = 0; nt < 4; nt++) acc[mt][nt] = (f32x4){0.f, 0.f, 0.f, 0.f};

  auto stage = [&](int buf, int k0){
    #pragma unroll
    for (int c = 0; c < 4; c++){
      const int q = wv * 4096 + c * 1024;            // wave-uniform LDS base
      const int row = (q >> 7) + (lane >> 3);        // per-lane row
      const int slot = (lane & 7) ^ (row & 7);       // logical slot to fetch
      gload16(A + (size_t)(m0 + row) * 1024 + k0 + slot * 8, &lds[buf][0][q]);
      gload16(B + (size_t)(n0 + row) * 1024 + k0 + slot * 8, &lds[buf][1][q]);
    }
  };

  stage(0, 0);
  __syncthreads();
  int cur = 0;
  for (int t = 0; t < 16; t++){
    if (t < 15) stage(cur ^ 1, (t + 1) * 64);
    const char* Abuf = lds[cur][0];
    const char* Bbuf = lds[cur][1];
    #pragma unroll
    for (int kk = 0; kk < 2; kk++){
      bf16x8 af[4], bfr[4];
      #pragma unroll
      for (int mt = 0; mt < 4; mt++){
        int r = wr * 64 + mt * 16 + lc;
        int slot = (kk * 4 + lh) ^ (r & 7);
        af[mt] = *(const bf16x8*)(const void*)(Abuf + r * 128 + slot * 16);
      }
      #pragma unroll
      for (int nt = 0; nt < 4; nt++){
        int r = wc * 64 + nt * 16 + lc;
        int slot = (kk * 4 + lh) ^ (r & 7);
        bfr[nt] = *(const bf16x8*)(const void*)(Bbuf + r * 128 + slot * 16);
      }
      #pragma unroll
      for (int mt = 0; mt < 4; mt++)
        #pragma unroll
        for (int nt = 0; nt < 4; nt++)
          acc[mt][nt] = MFMA16(af[mt], bfr[nt], acc[mt][nt]);
    }
    __syncthreads();
    cur ^= 1;
  }

  #pragma unroll
  for (int mt = 0; mt < 4; mt++)
    #pragma unroll
    for (int nt = 0; nt < 4; nt++)
      #pragma unroll
      for (int rg = 0; rg < 4; rg++){
        int row = m0 + wr * 64 + mt * 16 + lh * 4 + rg;
        int col = n0 + wc * 64 + nt * 16 + lc;
        if (F32OUT) ((float*)C)[(size_t)row * 1024 + col] = acc[mt][nt][rg];
        else ((bf16*)C)[(size_t)row * 1024 + col] = __float2bfloat16(acc[mt][nt][rg]);
      }
}

// ---------------------------------------------------------------------------
// K2: beta = sigmoid(x@Wb^T) stored [b][h][l]; mix = sigmoid(x@Wmix^T) [tok][h]
// ---------------------------------------------------------------------------
__global__ __launch_bounds__(256) void small_proj(
    const float* __restrict__ x, const float* __restrict__ Wb,
    const float* __restrict__ Wmix, float* __restrict__ beta, float* __restrict__ mixb)
{
  const int tok = blockIdx.x;
  const int tid = threadIdx.x;
  __shared__ __align__(16) float xrow[1024];
  ((float4*)xrow)[tid] = ((const float4*)(x + (size_t)tok * 1024))[tid];
  __syncthreads();
  const int o = tid >> 5, g = tid & 31;
  const float* Wrow = (o < 4) ? (Wb + (size_t)o * 1024) : (Wmix + (size_t)(o - 4) * 1024);
  float p = 0.f;
  for (int e = g; e < 256; e += 32){
    float4 xv = ((const float4*)xrow)[e];
    float4 wv = ((const float4*)Wrow)[e];
    p += xv.x * wv.x + xv.y * wv.y + xv.z * wv.z + xv.w * wv.w;
  }
  for (int off = 16; off; off >>= 1) p += __shfl_down(p, off, 32);
  if (g == 0){
    float s = 1.f / (1.f + expf(-p));
    int b = tok >> 12, t = tok & 4095;
    if (o < 4) beta[((size_t)(b * 4 + o)) * 4096 + t] = s;
    else       mixb[(size_t)tok * 4 + (o - 4)] = s;
  }
}

// ---------------------------------------------------------------------------
// K3: causal depthwise conv (K=4) + silu, vectorized bf16x8 (8 channels/thread)
// ---------------------------------------------------------------------------
__global__ __launch_bounds__(256) void conv_silu3(
    const bf16* __restrict__ in0, const bf16* __restrict__ in1, const bf16* __restrict__ in2,
    const float* __restrict__ w0, const float* __restrict__ w1, const float* __restrict__ w2,
    bf16* __restrict__ o0, bf16* __restrict__ o1, bf16* __restrict__ o2)
{
  const bf16* in; const float* wc; bf16* out;
  if (blockIdx.y == 0)      { in = in0; wc = w0; out = o0; }
  else if (blockIdx.y == 1) { in = in1; wc = w1; out = o1; }
  else                      { in = in2; wc = w2; out = o2; }
  const int idx8 = blockIdx.x * 256 + threadIdx.x;   // < 2097152
  const int c8 = (idx8 & 127) * 8;
  const int tt = idx8 >> 7;            // b*4096 + t
  const int t  = tt & 4095;
  const u16* inu = (const u16*)in;
  const size_t base = (size_t)tt * 1024 + c8;
  bf16x8 zv = {0, 0, 0, 0, 0, 0, 0, 0};
  bf16x8 x3 = *(const bf16x8*)(const void*)(inu + base);
  bf16x8 x2 = (t >= 1) ? *(const bf16x8*)(const void*)(inu + base - 1024) : zv;
  bf16x8 x1 = (t >= 2) ? *(const bf16x8*)(const void*)(inu + base - 2048) : zv;
  bf16x8 x0 = (t >= 3) ? *(const bf16x8*)(const void*)(inu + base - 3072) : zv;
  u16 o8[8];
  #pragma unroll
  for (int e = 0; e < 8; e++){
    const float4 w4 = ((const float4*)wc)[c8 + e];
    float s = w4.w * bfu2f((u16)x3[e]) + w4.z * bfu2f((u16)x2[e])
            + w4.y * bfu2f((u16)x1[e]) + w4.x * bfu2f((u16)x0[e]);
    s = s / (1.f + expf(-s));
    o8[e] = f2bfu(s);
  }
  *(bf16x8*)(void*)((u16*)out + base) = *(bf16x8*)o8;
}

// ---------------------------------------------------------------------------
// K4: per-chunk prep, MFMA version (unchanged, r5-proven).
// ---------------------------------------------------------------------------
__global__ __launch_bounds__(256, 2) void chunk_prep(
    bf16* __restrict__ qc, const bf16* __restrict__ kc, const bf16* __restrict__ vc,
    const float* __restrict__ beta,
    bf16* __restrict__ u_out, bf16* __restrict__ w_out,
    bf16* __restrict__ Ab, bf16* __restrict__ kTg)
{
  __shared__ char kS[16384], qS[16384];       // [32][256] bf16, row-swizzled
  __shared__ float att[1056];                 // [32][33] fp32
  __shared__ char Th[2048], Tl[2048];         // T hi/lo [32]x64B, group-swizzled
  __shared__ char vTh[8192], vTl[8192];       // vb^T half [128]x64B hi/lo
  __shared__ char wTh[8192], wTl[8192];       // kb^T half
  __shared__ float rnk_s[32], rnq_s[32], bvec[32];

  const int g = blockIdx.x;
  const int ch = g & 127, h = (g >> 7) & 3, b = g >> 9;
  const int tid = threadIdx.x;
  const int l = tid & 63, wv = tid >> 6;
  const int lc = l & 15, lh = l >> 4;
  const int i = tid >> 3, s = tid & 7;        // row, 32-col slice
  const size_t rowbase = ((size_t)(b * 4096 + ch * 32)) * 1024 + (size_t)h * 256;
  const u16* kcu = (const u16*)kc;
  const u16* qcu = (const u16*)qc;
  const u16* vcu = (const u16*)vc;

  // ---- P1: load + row sum-of-squares ----
  bf16x8 kr[4], qr[4], vr[4];
  float ssk = 0.f, ssq = 0.f;
  #pragma unroll
  for (int j4 = 0; j4 < 4; j4++){
    size_t eo = rowbase + (size_t)i * 1024 + s * 32 + j4 * 8;
    kr[j4] = *(const bf16x8*)(const void*)(kcu + eo);
    qr[j4] = *(const bf16x8*)(const void*)(qcu + eo);
    vr[j4] = *(const bf16x8*)(const void*)(vcu + eo);
    #pragma unroll
    for (int e = 0; e < 8; e++){
      float kv = bfu2f((u16)kr[j4][e]); ssk += kv * kv;
      float qv = bfu2f((u16)qr[j4][e]); ssq += qv * qv;
    }
  }
  #pragma unroll
  for (int off = 1; off < 8; off <<= 1){
    ssk += __shfl_xor(ssk, off, 64);
    ssq += __shfl_xor(ssq, off, 64);
  }
  if (s == 0){
    rnk_s[i] = 1.0f / sqrtf(ssk + 1e-6f);
    rnq_s[i] = 1.0f / sqrtf(ssq + 1e-6f);
  }
  if (tid < 32) bvec[tid] = beta[((size_t)(b * 4 + h)) * 4096 + ch * 32 + tid];
  __syncthreads();

  // ---- P2: normalize; stage kS/qS; write qn global; vT/kbT half 0 ----
  const float rk = rnk_s[i], rq = rnq_s[i], bi = bvec[i];
  #pragma unroll
  for (int j4 = 0; j4 < 4; j4++){
    u16 kn8[8], qn8[8];
    #pragma unroll
    for (int e = 0; e < 8; e++){
      kn8[e] = f2bfu(bfu2f((u16)kr[j4][e]) * rk);
      qn8[e] = f2bfu(bfu2f((u16)qr[j4][e]) * rq);
    }
    int byt = (i * 512 + s * 64 + j4 * 16) ^ ((i & 7) << 4);
    *(bf16x8*)(void*)(kS + byt) = *(bf16x8*)kn8;
    *(bf16x8*)(void*)(qS + byt) = *(bf16x8*)qn8;
    *(bf16x8*)(void*)((u16*)qc + rowbase + (size_t)i * 1024 + s * 32 + j4 * 8) = *(bf16x8*)kn8 * 0 + *(bf16x8*)qn8;
  }
  if ((s >> 2) == 0){
    #pragma unroll
    for (int j4 = 0; j4 < 4; j4++)
      #pragma unroll
      for (int e = 0; e < 8; e++){
        int dl = (s & 3) * 32 + j4 * 8 + e;
        float vb = bfu2f((u16)vr[j4][e]) * bi;
        float kb = bfu2f((u16)kr[j4][e]) * rk * bi;
        u16 vh = f2bfu(vb), kh = f2bfu(kb);
        u16 vlo = f2bfu(vb - bfu2f(vh)), klo = f2bfu(kb - bfu2f(kh));
        int byt = dl * 64 + (((i >> 3) ^ ((dl >> 1) & 3)) << 4) + (i & 7) * 2;
        *(u16*)(vTh + byt) = vh; *(u16*)(vTl + byt) = vlo;
        *(u16*)(wTh + byt) = kh; *(u16*)(wTl + byt) = klo;
      }
  }
  __syncthreads();

  // ---- P3: L & A quadrants via MFMA; kTg transpose-out ----
  {
    const int mq = wv >> 1, nq = wv & 1;
    const int rowA = mq * 16 + lc, rowB = nq * 16 + lc;
    const int swA = (rowA & 7) << 4, swB = (rowB & 7) << 4;
    f32x4 accL = (f32x4){0.f, 0.f, 0.f, 0.f};
    f32x4 accA = (f32x4){0.f, 0.f, 0.f, 0.f};
    #pragma unroll
    for (int kt = 0; kt < 8; kt++){
      bf16x8 af  = *(const bf16x8*)(const void*)(kS + ((rowA * 512 + kt * 64 + lh * 16) ^ swA));
      bf16x8 bf_ = *(const bf16x8*)(const void*)(kS + ((rowB * 512 + kt * 64 + lh * 16) ^ swB));
      bf16x8 aq  = *(const bf16x8*)(const void*)(qS + ((rowA * 512 + kt * 64 + lh * 16) ^ swA));
      accL = MFMA16(af, bf_, accL);
      accA = MFMA16(aq, bf_, accA);
    }
    #pragma unroll
    for (int r = 0; r < 4; r++){
      int rr = mq * 16 + lh * 4 + r, cc = nq * 16 + lc;
      att[rr * 33 + cc] = (cc < rr) ? (-bvec[rr] * accL[r]) : 0.f;
      float av = (cc <= rr) ? accA[r] : 0.f;
      ((u16*)Ab)[(size_t)g * 1024 + rr * 32 + cc] = f2bfu(av);
    }
  }
  {
    u16 tmp[32];
    #pragma unroll
    for (int i2 = 0; i2 < 32; i2++)
      tmp[i2] = *(const u16*)(kS + ((i2 * 512 + tid * 2) ^ ((i2 & 7) << 4)));
    #pragma unroll
    for (int j4 = 0; j4 < 4; j4++)
      *(bf16x8*)(void*)((u16*)kTg + (size_t)g * 8192 + tid * 32 + j4 * 8) = *(bf16x8*)(tmp + j4 * 8);
  }
  __syncthreads();

  // ---- P4: wave-0 fp32 forward substitution (barrier-free in-wave) ----
  if (wv == 0 && l < 32){
    for (int ii = 1; ii < 32; ii++){
      float upd = 0.f;
      for (int m = 0; m < ii; m++)
        upd += att[ii * 33 + m] * att[m * 33 + l];
      att[ii * 33 + l] += upd;
    }
    att[l * 33 + l] = 1.0f;   // T = subst(L) + I
  }
  __syncthreads();

  // ---- P5: T -> hi/lo bf16 ----
  #pragma unroll
  for (int z = 0; z < 4; z++){
    int e = tid * 4 + z;
    int row = e >> 5, col = e & 31;
    float f = att[row * 33 + col];
    u16 hh = f2bfu(f), llo = f2bfu(f - bfu2f(hh));
    int byt = row * 64 + ((((col >> 3)) ^ ((row >> 1) & 3)) << 4) + (col & 7) * 2;
    *(u16*)(Th + byt) = hh; *(u16*)(Tl + byt) = llo;
  }
  __syncthreads();

  // ---- P6/P8: u = T@vb, w = T@kb (3-term hi/lo), two dv halves ----
  {
    const int mq = wv >> 1, nsel = wv & 1;
    const int rowA = mq * 16 + lc;
    const int sa = (lh ^ ((rowA >> 1) & 3)) << 4;
    bf16x8 ta = *(const bf16x8*)(const void*)(Th + rowA * 64 + sa);
    bf16x8 tl = *(const bf16x8*)(const void*)(Tl + rowA * 64 + sa);
    #pragma unroll
    for (int half = 0; half < 2; half++){
      if (half == 1){
        __syncthreads();            // all half-0 reads done
        if ((s >> 2) == 1){         // P7: stage half 1
          #pragma unroll
          for (int j4 = 0; j4 < 4; j4++)
            #pragma unroll
            for (int e = 0; e < 8; e++){
              int dl = (s & 3) * 32 + j4 * 8 + e;
              float vb = bfu2f((u16)vr[j4][e]) * bi;
              float kb = bfu2f((u16)kr[j4][e]) * rk * bi;
              u16 vh = f2bfu(vb), kh = f2bfu(kb);
              u16 vlo = f2bfu(vb - bfu2f(vh)), klo = f2bfu(kb - bfu2f(kh));
              int byt = dl * 64 + (((i >> 3) ^ ((dl >> 1) & 3)) << 4) + (i & 7) * 2;
              *(u16*)(vTh + byt) = vh; *(u16*)(vTl + byt) = vlo;
              *(u16*)(wTh + byt) = kh; *(u16*)(wTl + byt) = klo;
            }
        }
        __syncthreads();
      }
      #pragma unroll
      for (int nt = 0; nt < 4; nt++){
        int nl = nsel * 64 + nt * 16;
        int rowB = nl + lc;
        int sb = (lh ^ ((rowB >> 1) & 3)) << 4;
        bf16x8 bh_ = *(const bf16x8*)(const void*)(vTh + rowB * 64 + sb);
        bf16x8 bl_ = *(const bf16x8*)(const void*)(vTl + rowB * 64 + sb);
        f32x4 aU = (f32x4){0.f, 0.f, 0.f, 0.f};
        aU = MFMA16(ta, bh_, aU);
        aU = MFMA16(ta, bl_, aU);
        aU = MFMA16(tl, bh_, aU);
        bf16x8 wh_ = *(const bf16x8*)(const void*)(wTh + rowB * 64 + sb);
        bf16x8 wl_ = *(const bf16x8*)(const void*)(wTl + rowB * 64 + sb);
        f32x4 aW = (f32x4){0.f, 0.f, 0.f, 0.f};
        aW = MFMA16(ta, wh_, aW);
        aW = MFMA16(ta, wl_, aW);
        aW = MFMA16(tl, wh_, aW);
        #pragma unroll
        for (int r = 0; r < 4; r++){
          int row = mq * 16 + lh * 4 + r, col = half * 128 + nl + lc;
          ((u16*)u_out)[rowbase + (size_t)row * 1024 + col] = f2bfu(aU[r]);
          ((u16*)w_out)[rowbase + (size_t)row * 1024 + col] = f2bfu(aW[r]);
        }
      }
    }
  }
}

// ---------------------------------------------------------------------------
// K5: sequential chunk scan — r12 version verbatim (best proven: 254 us).
// 256 blocks x 128 thr (2 waves); 16-col slice per block; kT frags direct
// from global; w/q staged via global_load_lds with inverse-swizzled source;
// two __syncthreads per chunk. LDS 84480 B.
// ---------------------------------------------------------------------------
__global__ __launch_bounds__(128, 1) void scan_kernel(
    const u16* __restrict__ w_in, const u16* __restrict__ qn,
    const u16* __restrict__ u_in, const bf16* __restrict__ Ab,
    const bf16* __restrict__ kTg, bf16* __restrict__ o_out)
{
  extern __shared__ char smem[];
  char* wqbuf  = smem;               // [2][w:16K | q:16K], rows 512B swizzled
  char* stbuf  = smem + 65536;       // S^T hi 8K | lo 8K ([16 c][512B]) swizzled
  char* untbuf = smem + 81920;       // un^T hi 1280 | lo 1280 ([16 c][80B])

  const int tid = threadIdx.x;                 // 0..127
  const int l = tid & 63, wv = tid >> 6;       // wv 0..1
  const int lc = l & 15, lh = l >> 4;
  const int wg = blockIdx.x;
  const int bh = (wg & 7) * 2 + ((wg >> 3) & 1);  // all 16 vb of a bh on one XCD
  const int vb = wg >> 4;                      // 0..15
  const int h = bh & 3, b = bh >> 2;
  const int c0 = vb * 16;
  const int mw = wv * 16;                      // wave's un-row block

  f32x4 Sf[8];
  #pragma unroll
  for (int mt = 0; mt < 8; mt++) Sf[mt] = (f32x4){0.f, 0.f, 0.f, 0.f};

  const size_t bhElem = (size_t)b * 4096 * 1024 + (size_t)h * 256;
  const u16* kTu = (const u16*)kTg;

  auto stageWQ = [&](int buf, size_t rowE){
    char* wbase = wqbuf + buf * 32768 + wv * 8192;
    #pragma unroll
    for (int p = 0; p < 8; p++){
      int i = wv * 16 + p * 2 + (l >> 5);      // row this lane covers
      int logc = (l & 31) ^ (i & 7);           // logical 16B chunk to fetch
      size_t src = rowE + (size_t)i * 1024 + (size_t)logc * 8;
      gload16(w_in + src, wbase + p * 1024);
      gload16(qn  + src, wbase + 16384 + p * 1024);
    }
  };

  // prologue: stage chunk 0; zero S^T; chunk-0 u/A frags
  stageWQ(0, bhElem);
  for (int e = tid; e < 4096; e += 128) ((unsigned int*)(void*)stbuf)[e] = 0u;
  u16 cu0 = u_in[bhElem + (size_t)(mw + lh*4 + 0) * 1024 + c0 + lc];
  u16 cu1 = u_in[bhElem + (size_t)(mw + lh*4 + 1) * 1024 + c0 + lc];
  u16 cu2 = u_in[bhElem + (size_t)(mw + lh*4 + 2) * 1024 + c0 + lc];
  u16 cu3 = u_in[bhElem + (size_t)(mw + lh*4 + 3) * 1024 + c0 + lc];
  bf16x8 cAf = *(const bf16x8*)(const void*)(Ab + (size_t)(bh * 128) * 1024 + (mw + lc) * 32 + lh * 8);
  __syncthreads();

  int cur = 0;
  for (int ch = 0; ch < 128; ch++){
    const size_t rowElem = bhElem + (size_t)ch * 32768;
    if (ch < 127) stageWQ(cur ^ 1, rowElem + 32768);
    bf16x8 kF[8];
    {
      const size_t ktCur = (size_t)(bh * 128 + ch) * 8192;
      #pragma unroll
      for (int mt = 0; mt < 8; mt++){
        int rowK = wv * 128 + mt * 16 + lc;
        kF[mt] = *(const bf16x8*)(const void*)(kTu + ktCur + (size_t)rowK * 32 + lh * 8);
      }
    }
    u16 pu0, pu1, pu2, pu3; bf16x8 pAf;
    if (ch < 127){
      const size_t rowN = rowElem + 32768;
      pu0 = u_in[rowN + (size_t)(mw + lh*4 + 0) * 1024 + c0 + lc];
      pu1 = u_in[rowN + (size_t)(mw + lh*4 + 1) * 1024 + c0 + lc];
      pu2 = u_in[rowN + (size_t)(mw + lh*4 + 2) * 1024 + c0 + lc];
      pu3 = u_in[rowN + (size_t)(mw + lh*4 + 3) * 1024 + c0 + lc];
      pAf = *(const bf16x8*)(const void*)(Ab + (size_t)(bh * 128 + ch + 1) * 1024 + (mw + lc) * 32 + lh * 8);
    }

    const char* wl = wqbuf + cur * 32768;
    const char* ql = wl + 16384;

    // fused phase: accU = w@S, accO = q@S (old S), even/odd-kt split chains
    f32x4 aU0 = (f32x4){0.f,0.f,0.f,0.f}, aU1 = (f32x4){0.f,0.f,0.f,0.f};
    f32x4 aO0 = (f32x4){0.f,0.f,0.f,0.f}, aO1 = (f32x4){0.f,0.f,0.f,0.f};
    {
      const int rowA = mw + lc;
      const int swA = (rowA & 7) << 4;
      const int swS = (lc & 7) << 4;
      #pragma unroll
      for (int kt = 0; kt < 8; kt++){
        const int kb = kt * 64 + lh * 16;
        bf16x8 aw = *(const bf16x8*)(const void*)(wl + ((rowA * 512 + kb) ^ swA));
        bf16x8 aq = *(const bf16x8*)(const void*)(ql + ((rowA * 512 + kb) ^ swA));
        bf16x8 sh = *(const bf16x8*)(const void*)(stbuf + ((lc * 512 + kb) ^ swS));
        bf16x8 sl = *(const bf16x8*)(const void*)(stbuf + 8192 + ((lc * 512 + kb) ^ swS));
        if (kt & 1){
          aU1 = MFMA16(aw, sh, aU1);
          aU1 = MFMA16(aw, sl, aU1);
          aO1 = MFMA16(aq, sh, aO1);
          aO1 = MFMA16(aq, sl, aO1);
        } else {
          aU0 = MFMA16(aw, sh, aU0);
          aU0 = MFMA16(aw, sl, aU0);
          aO0 = MFMA16(aq, sh, aO0);
          aO0 = MFMA16(aq, sl, aO0);
        }
      }
    }
    f32x4 accO = aO0 + aO1;
    {
      f32x4 accU = aU0 + aU1;
      float v0 = bfu2f(cu0) - accU[0];
      float v1 = bfu2f(cu1) - accU[1];
      float v2 = bfu2f(cu2) - accU[2];
      float v3 = bfu2f(cu3) - accU[3];
      u16 h0 = f2bfu(v0), h1 = f2bfu(v1), h2 = f2bfu(v2), h3 = f2bfu(v3);
      u16 l0 = f2bfu(v0 - bfu2f(h0)), l1 = f2bfu(v1 - bfu2f(h1));
      u16 l2 = f2bfu(v2 - bfu2f(h2)), l3 = f2bfu(v3 - bfu2f(h3));
      unsigned int ph0 = (unsigned)h0 | ((unsigned)h1 << 16), ph1 = (unsigned)h2 | ((unsigned)h3 << 16);
      unsigned int pl0 = (unsigned)l0 | ((unsigned)l1 << 16), pl1 = (unsigned)l2 | ((unsigned)l3 << 16);
      int off = lc * 80 + (mw + lh * 4) * 2;
      *(u32x2*)(void*)(untbuf + off)        = (u32x2){ph0, ph1};
      *(u32x2*)(void*)(untbuf + 1280 + off) = (u32x2){pl0, pl1};
    }
    __syncthreads();   // barrier A: un^T visible; all stbuf reads done

    bf16x8 uh = *(const bf16x8*)(const void*)(untbuf + lc * 80 + lh * 16);
    bf16x8 ul = *(const bf16x8*)(const void*)(untbuf + 1280 + lc * 80 + lh * 16);
    accO = MFMA16(cAf, uh, accO);
    accO = MFMA16(cAf, ul, accO);
    o_out[rowElem + (size_t)(mw + lh*4 + 0) * 1024 + c0 + lc] = __float2bfloat16(accO[0]);
    o_out[rowElem + (size_t)(mw + lh*4 + 1) * 1024 + c0 + lc] = __float2bfloat16(accO[1]);
    o_out[rowElem + (size_t)(mw + lh*4 + 2) * 1024 + c0 + lc] = __float2bfloat16(accO[2]);
    o_out[rowElem + (size_t)(mw + lh*4 + 3) * 1024 + c0 + lc] = __float2bfloat16(accO[3]);

    #pragma unroll
    for (int mt = 0; mt < 8; mt++){
      Sf[mt] = MFMA16(kF[mt], uh, Sf[mt]);
      Sf[mt] = MFMA16(kF[mt], ul, Sf[mt]);
    }

    #pragma unroll
    for (int mt = 0; mt < 8; mt++){
      const int dbase = wv * 128 + mt * 16 + lh * 4;
      float v0 = Sf[mt][0], v1 = Sf[mt][1], v2 = Sf[mt][2], v3 = Sf[mt][3];
      u16 h0 = f2bfu(v0), h1 = f2bfu(v1), h2 = f2bfu(v2), h3 = f2bfu(v3);
      u16 s0 = f2bfu(v0 - bfu2f(h0)), s1 = f2bfu(v1 - bfu2f(h1));
      u16 s2 = f2bfu(v2 - bfu2f(h2)), s3 = f2bfu(v3 - bfu2f(h3));
      int off = ((lc * 512 + dbase * 2) ^ ((lc & 7) << 4));
      *(u32x2*)(void*)(stbuf + off) =
          (u32x2){(unsigned)h0 | ((unsigned)h1 << 16), (unsigned)h2 | ((unsigned)h3 << 16)};
      *(u32x2*)(void*)(stbuf + 8192 + off) =
          (u32x2){(unsigned)s0 | ((unsigned)s1 << 16), (unsigned)s2 | ((unsigned)s3 << 16)};
    }
    if (ch < 127){
      cu0 = pu0; cu1 = pu1; cu2 = pu2; cu3 = pu3; cAf = pAf;
    }
    __syncthreads();   // barrier C: staging + new S^T visible
    cur ^= 1;
  }
}

// ---------------------------------------------------------------------------
// K6: o = mix*o + (1-mix)*v_token ; RMS-norm over dv=256 * norm_w -> bf16
// Vectorized: 8 slots of (tok,h) per block; 32 lanes x bf16x8 per slot.
// ---------------------------------------------------------------------------
__global__ __launch_bounds__(256) void postproc(
    const bf16* __restrict__ o_in, const bf16* __restrict__ v_tok,
    const float* __restrict__ mixb, const float* __restrict__ norm_w,
    bf16* __restrict__ onorm)
{
  const int tid = threadIdx.x;
  const int slot = tid >> 5, g = tid & 31;     // slot 0..7, lane-in-slot
  const int blk = blockIdx.x * 8 + slot;       // (tok*4 + h), < 65536
  const size_t base = (size_t)blk * 256 + g * 8;
  const u16* oin = (const u16*)o_in;
  const u16* vin = (const u16*)v_tok;
  bf16x8 ov8 = *(const bf16x8*)(const void*)(oin + base);
  bf16x8 vv8 = *(const bf16x8*)(const void*)(vin + base);
  float m = mixb[blk];
  float val[8];
  float ss = 0.f;
  #pragma unroll
  for (int e = 0; e < 8; e++){
    float v = m * bfu2f((u16)ov8[e]) + (1.f - m) * bfu2f((u16)vv8[e]);
    val[e] = v;
    ss += v * v;
  }
  #pragma unroll
  for (int off = 16; off; off >>= 1) ss += __shfl_down(ss, off, 32);
  ss = __shfl(ss, 0, 32);
  float r = rsqrtf(ss * (1.f / 256.f) + 1e-5f);
  const float4 nw0 = ((const float4*)norm_w)[g * 2];
  const float4 nw1 = ((const float4*)norm_w)[g * 2 + 1];
  const float nw[8] = {nw0.x, nw0.y, nw0.z, nw0.w, nw1.x, nw1.y, nw1.z, nw1.w};
  u16 o8[8];
  #pragma unroll
  for (int e = 0; e < 8; e++) o8[e] = f2bfu(val[e] * r * nw[e]);
  *(bf16x8*)(void*)((u16*)onorm + base) = *(bf16x8*)o8;
}

// ---------------------------------------------------------------------------
// Workspace budget (<= round-2-proven 239,599,616 bytes). Aliases:
//   xbf = b4 region ; wqb/wkb/wvb = front of b3 ; wob = kTg region (post-scan)
// ---------------------------------------------------------------------------
extern "C" void kernel_launch(void* const* d_in, const int* in_sizes, int n_in,
                              void* d_out, int out_size, void* d_ws, size_t ws_size,
                              hipStream_t stream)
{
  (void)in_sizes; (void)n_in; (void)out_size; (void)ws_size;
  const float* x     = (const float*)d_in[0];
  const float* Wq    = (const float*)d_in[1];
  const float* Wk    = (const float*)d_in[2];
  const float* Wv    = (const float*)d_in[3];
  const float* convq = (const float*)d_in[4];
  const float* convk = (const float*)d_in[5];
  const float* convv = (const float*)d_in[6];
  const float* Wb    = (const float*)d_in[7];
  const float* Wmix  = (const float*)d_in[8];
  const float* normw = (const float*)d_in[9];
  const float* Wo    = (const float*)d_in[10];
  float* out = (float*)d_out;

  char* wsb = (char*)d_ws;
  const size_t BIGB = (size_t)16777216 * 2;   // one bf16 [16384][1024] buffer
  bf16* b0 = (bf16*)(wsb + 0*BIGB);  // qlin -> later w
  bf16* b1 = (bf16*)(wsb + 1*BIGB);  // klin -> later o
  bf16* b2 = (bf16*)(wsb + 2*BIGB);  // vlin -> later u
  bf16* b3 = (bf16*)(wsb + 3*BIGB);  // (wq/wk/wv bf16) -> qc -> qn -> onorm
  bf16* b4 = (bf16*)(wsb + 4*BIGB);  // (x bf16) -> kc
  bf16* b5 = (bf16*)(wsb + 5*BIGB);  // vc (v_token, persistent)
  bf16*  Ab   = (bf16*) (wsb + 6*BIGB);                            // 4MiB
  float* beta = (float*)(wsb + 6*BIGB + 4194304);                  // 256KiB
  float* mixb = beta + 65536;                                      // 256KiB
  bf16*  kTg  = (bf16*) (wsb + 6*BIGB + 4194304 + 524288);         // 32MiB

  u16* xbf = (u16*)b4;
  u16* wqb = (u16*)b3;
  u16* wkb = wqb + (size_t)1024*1024;
  u16* wvb = wkb + (size_t)1024*1024;
  u16* wob = (u16*)kTg;

  cvt_bf16<<<8192, 256, 0, stream>>>(x, xbf, 2097152);
  cvt3_bf16<<<dim3(512, 3), 256, 0, stream>>>(Wq, Wk, Wv, wqb, wkb, wvb);

  gemm_bt<3, false><<<dim3(128, 8, 3), 256, 0, stream>>>(
      xbf, wqb, wkb, wvb, (void*)b0, (void*)b1, (void*)b2);
  small_proj<<<16384, 256, 0, stream>>>(x, Wb, Wmix, beta, mixb);
  conv_silu3<<<dim3(8192, 3), 256, 0, stream>>>(
      b0, b1, b2, convq, convk, convv, b3, b4, b5);
  chunk_prep<<<2048, 256, 0, stream>>>(b3, b4, b5, beta, b2, b0, Ab, kTg);
  hipFuncSetAttribute((const void*)scan_kernel,
                      hipFuncAttributeMaxDynamicSharedMemorySize, 84480);
  scan_kernel<<<256, 128, 84480, stream>>>((const u16*)b0, (const u16*)b3,
                                           (const u16*)b2, Ab, kTg, b1);
  cvt_bf16<<<512, 256, 0, stream>>>(Wo, wob, 131072);   // kTg dead after scan
  postproc  <<<8192, 256, 0, stream>>>(b1, b5, mixb, normw, b3);
  gemm_bt<1, true><<<dim3(128, 8, 1), 256, 0, stream>>>(
      (const u16*)b3, wob, wob, wob, (void*)out, (void*)out, (void*)out);
}